// Round 7
// baseline (399.162 us; speedup 1.0000x reference)
//
#include <hip/hip_runtime.h>

// ---------------------------------------------------------------------------
// ProteinGCNNet: 3x GCNConv + mean-pool + 2 FC layers.
// Round 22: (1) 8-deep predicated batch-issue in ALL gathers: edges [0,32)
// issue as 8 back-to-back exec-masked f16x8 loads (shfl'd indices computed
// unconditionally first), ONE exposed latency per node for deg<=32 (97%+)
// vs the old 4x/2x/1x ladder's ~3. (2) k_bkt_hist folded into k_init (same
// 391-block grid); k_prescale folded into k_bkt_build's tail (dinv stashed
// in LDS). 13 -> 11 dispatches. Two-nodes-per-wave fused gather, L3 split,
// bucketed CSR, MFMA GEMMs, fused pool, split FC head all kept (R21 base,
// 385.7us).
// ---------------------------------------------------------------------------

typedef _Float16 f16;
typedef _Float16 f16x2 __attribute__((ext_vector_type(2)));
typedef _Float16 f16x8 __attribute__((ext_vector_type(8)));
typedef float f32x4 __attribute__((ext_vector_type(4)));

static __host__ __device__ inline int cdiv(int a, int b) { return (a + b - 1) / b; }

constexpr int BSPAN = 512;
constexpr int EPB   = 4096;
constexpr int EPT   = EPB / 256;

// ---- MFMA weight pack helper ----------------------------------------------
__device__ __forceinline__ void wpack_one(const float* W, f16* Wb, int K, int F,
                                          int KT, int idx) {
    int j = idx & 7;
    int lane = (idx >> 3) & 63;
    int fi = idx >> 9;
    int kt = fi % KT;
    int nt = fi / KT;
    int k = kt * 32 + (lane >> 4) * 8 + j;
    int nn = nt * 16 + (lane & 15);
    Wb[idx] = (k < K && nn < F) ? (f16)W[k * F + nn] : (f16)0.f;
}

// ---- combined init: zero + weight pack + boundaries + bucket histogram -----
__global__ __launch_bounds__(256) void k_init(
        const int* __restrict__ batch, int* __restrict__ start,
        float* __restrict__ psum, int* __restrict__ bktCnt, int* __restrict__ bktCur,
        const int* __restrict__ col,
        const float* __restrict__ W1, const float* __restrict__ W2,
        const float* __restrict__ W3, f16* __restrict__ w1b,
        f16* __restrict__ w2b, f16* __restrict__ w3b,
        int e, int nb, int n, int g) {
    __shared__ int hist[256];
    int t = threadIdx.x;
    int i = blockIdx.x * blockDim.x + t;
    hist[t] = 0;
    __syncthreads();
    // bucket histogram portion (was k_bkt_hist)
    int ebase = blockIdx.x * EPB;
#pragma unroll
    for (int j = 0; j < EPT; j++) {
        int idx = ebase + j * 256 + t;
        if (idx < e) atomicAdd(&hist[col[idx] >> 9], 1);
    }
    // independent init work overlaps the hist atomics
    if (i < g * 216) psum[i] = 0.f;
    if (i < 256) bktCur[i] = 0;
    constexpr int T1 = 4 * 2 * 512;
    constexpr int T2 = 7 * 2 * 512;
    constexpr int T3 = 14 * 4 * 512;
    if (i < T1) wpack_one(W1, w1b, 54, 54, 2, i);
    else if (i < T1 + T2) wpack_one(W2, w2b, 54, 108, 2, i - T1);
    else if (i < T1 + T2 + T3) wpack_one(W3, w3b, 108, 216, 4, i - T1 - T2);
    if (i < n) {
        int b = batch[i];
        int bp = (i == 0) ? -1 : batch[i - 1];
        for (int gg = bp + 1; gg <= b; gg++) start[gg] = i;
        if (i == n - 1)
            for (int gg = b + 1; gg <= g; gg++) start[gg] = n;
    }
    __syncthreads();
    if (t < nb && hist[t] > 0) atomicAdd(&bktCnt[t], hist[t]);
}

// ---- in-block exclusive scan ------------------------------------------------
__device__ __forceinline__ int scan256_ex(int* sbuf, int v, int t) {
    sbuf[t] = v;
    __syncthreads();
    for (int off = 1; off < 256; off <<= 1) {
        int x = sbuf[t];
        int y = (t >= off) ? sbuf[t - off] : 0;
        __syncthreads();
        sbuf[t] = x + y;
        __syncthreads();
    }
    return sbuf[t] - v;
}

// ---- A2: partition edges; ebuf packed (ldst<<17)|src (N < 2^17) ------------
__global__ __launch_bounds__(256) void k_bkt_part(const int* __restrict__ row,
                                                  const int* __restrict__ col,
                                                  const int* __restrict__ bktCnt,
                                                  int* bktCur, unsigned int* __restrict__ ebuf,
                                                  int e, int nb) {
    __shared__ int sbuf[256];
    __shared__ int hist[256];
    __shared__ int base[256];
    __shared__ int lcur[256];
    int t = threadIdx.x;
    int boff = scan256_ex(sbuf, (t < nb) ? bktCnt[t] : 0, t);
    hist[t] = 0; lcur[t] = 0;
    __syncthreads();
    int bs = blockIdx.x * EPB;
    unsigned int pk[EPT];
    int b[EPT];
#pragma unroll
    for (int j = 0; j < EPT; j++) {
        int idx = bs + j * 256 + t;
        if (idx < e) {
            int c = col[idx];
            pk[j] = ((unsigned int)(c & (BSPAN - 1)) << 17) | (unsigned int)row[idx];
            b[j] = c >> 9;
            atomicAdd(&hist[b[j]], 1);
        } else b[j] = -1;
    }
    __syncthreads();
    if (t < nb && hist[t] > 0) base[t] = boff + atomicAdd(&bktCur[t], hist[t]);
    __syncthreads();
#pragma unroll
    for (int j = 0; j < EPT; j++) {
        if (b[j] >= 0) {
            int lofs = atomicAdd(&lcur[b[j]], 1);
            ebuf[base[b[j]] + lofs] = pk[j];
        }
    }
}

// ---- B: per-bucket hist+scan -> rowptr + dinv + CSR fill + prescale --------
__global__ __launch_bounds__(256) void k_bkt_build(const unsigned int* __restrict__ ebuf,
                                                   const int* __restrict__ bktCnt,
                                                   int* __restrict__ rowptr,
                                                   float* __restrict__ dinv,
                                                   int* __restrict__ eSrc,
                                                   const float* __restrict__ x,
                                                   f16* __restrict__ xs,
                                                   int n, int nb) {
    __shared__ int sbuf[256];
    __shared__ int hist[BSPAN];
    __shared__ int cur[BSPAN];
    __shared__ float sdinv[BSPAN];
    int t = threadIdx.x;
    int bkt = blockIdx.x;

    int boff_ex = scan256_ex(sbuf, (t < nb) ? bktCnt[t] : 0, t);
    __shared__ int boff_s, cnt_s;
    if (t == bkt) boff_s = boff_ex;
    if (t == 0) cnt_s = bktCnt[bkt];
    hist[t] = 0; hist[t + 256] = 0;
    __syncthreads();
    int es = boff_s, ee = boff_s + cnt_s;

    // 4x-unrolled hist pass (196 blocks -> latency-exposed; batch loads)
    {
        int i = es + t;
        for (; i + 3 * 256 < ee; i += 4 * 256) {
            unsigned p0 = ebuf[i], p1 = ebuf[i + 256], p2 = ebuf[i + 512], p3 = ebuf[i + 768];
            atomicAdd(&hist[p0 >> 17], 1);
            atomicAdd(&hist[p1 >> 17], 1);
            atomicAdd(&hist[p2 >> 17], 1);
            atomicAdd(&hist[p3 >> 17], 1);
        }
        for (; i < ee; i += 256) atomicAdd(&hist[ebuf[i] >> 17], 1);
    }
    __syncthreads();

    int h0 = hist[2 * t], h1 = hist[2 * t + 1];
    __syncthreads();
    int ex = scan256_ex(sbuf, h0 + h1, t);
    int e0 = es + ex, e1 = e0 + h0;

    int node0 = bkt * BSPAN;
    int n0 = node0 + 2 * t, n1 = node0 + 2 * t + 1;
    float d0 = rsqrtf((float)(h0 + 1)), d1 = rsqrtf((float)(h1 + 1));
    if (n0 <= n) rowptr[n0] = e0;
    if (n1 <= n) rowptr[n1] = e1;
    if (n0 < n) dinv[n0] = d0;
    if (n1 < n) dinv[n1] = d1;
    sdinv[2 * t] = d0; sdinv[2 * t + 1] = d1;
    cur[2 * t] = e0; cur[2 * t + 1] = e1;
    __syncthreads();

    // 4x-unrolled fill pass
    {
        int i = es + t;
        for (; i + 3 * 256 < ee; i += 4 * 256) {
            unsigned p0 = ebuf[i], p1 = ebuf[i + 256], p2 = ebuf[i + 512], p3 = ebuf[i + 768];
            int s0 = atomicAdd(&cur[p0 >> 17], 1);
            int s1 = atomicAdd(&cur[p1 >> 17], 1);
            int s2 = atomicAdd(&cur[p2 >> 17], 1);
            int s3 = atomicAdd(&cur[p3 >> 17], 1);
            eSrc[s0] = (int)(p0 & 0x1FFFFu);
            eSrc[s1] = (int)(p1 & 0x1FFFFu);
            eSrc[s2] = (int)(p2 & 0x1FFFFu);
            eSrc[s3] = (int)(p3 & 0x1FFFFu);
        }
        for (; i < ee; i += 256) {
            unsigned int p = ebuf[i];
            int slot = atomicAdd(&cur[p >> 17], 1);
            eSrc[slot] = (int)(p & 0x1FFFFu);
        }
    }

    // fused prescale: xs[node][c] = f16(dinv[node] * x[node][c]), stride 64
    for (int idx = t; idx < BSPAN * 27; idx += 256) {
        int nl = idx / 27;
        int c = idx - nl * 27;
        int node = node0 + nl;
        if (node < n) {
            float d = sdinv[nl];
            float2 v = *reinterpret_cast<const float2*>(x + (long long)node * 54 + c * 2);
            f16x2 h;
            h[0] = (f16)(v.x * d);
            h[1] = (f16)(v.y * d);
            *reinterpret_cast<f16x2*>(xs + (long long)node * 64 + c * 2) = h;
        }
    }
}

// ---- wide gather, 8-deep predicated batch issue (standalone, layer 3) ------
template <int F, int RS>
__global__ __launch_bounds__(256) void k_gatherw(
        const int* __restrict__ rowptr, const int* __restrict__ eSrc,
        const float* __restrict__ dinv, const f16* __restrict__ hs,
        f16* __restrict__ out, int n) {
    constexpr int CGN = RS / 8;    // f16x8 chunks per row (16 for RS=128)
    constexpr int EPW = 64 / CGN;  // rows gathered per wave instr (4)
    int wave = threadIdx.x >> 6;
    int lane = threadIdx.x & 63;
    int eslot = lane / CGN;
    int cg = lane & (CGN - 1);
    int node = blockIdx.x * 4 + wave;
    if (node >= n) return;
    int ch0 = cg * 8;
    int lim = F - ch0;
    if (lim > 8) lim = 8;
    if (lim < 0) lim = 0;

    int rs_ = rowptr[node], re = rowptr[node + 1];
    float di = dinv[node];
    int deg = re - rs_;
    int myidx = 0;
    if (lane < deg) myidx = eSrc[rs_ + lane];

    const f16x8* src = reinterpret_cast<const f16x8*>(hs);
    float acc[8];
#pragma unroll
    for (int j = 0; j < 8; j++) acc[j] = 0.f;

    if (eslot == 0) {
        f16x8 v = src[(long long)node * CGN + cg];
#pragma unroll
        for (int j = 0; j < 8; j++) acc[j] += (float)v[j];
    }

    int nfull = deg < 64 ? deg : 64;
    // 8-deep batch issue: 32 edges per round, 1-2 rounds (2nd rare, uniform)
    for (int base = 0; base < nfull; base += 8 * EPW) {
        int sidx[8];
#pragma unroll
        for (int u = 0; u < 8; u++) {
            int idx = base + u * EPW + eslot;
            sidx[u] = __shfl(myidx, idx < 63 ? idx : 63);
        }
        f16x8 v[8];
#pragma unroll
        for (int u = 0; u < 8; u++) {
            int idx = base + u * EPW + eslot;
            if (idx < nfull) v[u] = src[(long long)sidx[u] * CGN + cg];
        }
#pragma unroll
        for (int u = 0; u < 8; u++) {
            int idx = base + u * EPW + eslot;
            if (idx < nfull) {
#pragma unroll
                for (int j = 0; j < 8; j++) acc[j] += (float)v[u][j];
            }
        }
    }
    // overflow beyond 64 preloaded edges (rare)
    for (int e = rs_ + 64 + eslot; e < re; e += EPW) {
        int s = eSrc[e];
        f16x8 v = src[(long long)s * CGN + cg];
#pragma unroll
        for (int j = 0; j < 8; j++) acc[j] += (float)v[j];
    }

#pragma unroll
    for (int j = 0; j < 8; j++)
        if (j >= lim) acc[j] = 0.f;
#pragma unroll
    for (int m = CGN; m < 64; m <<= 1)
#pragma unroll
        for (int j = 0; j < 8; j++) acc[j] += __shfl_xor(acc[j], m);

    if (eslot == 0) {
        f16x8 o;
#pragma unroll
        for (int j = 0; j < 8; j++) o[j] = (f16)(acc[j] * di);
        *reinterpret_cast<f16x8*>(out + (long long)node * RS + ch0) = o;
    }
}

// ---- fused gather + MFMA GEMM (layers 1/2: F=54, KPAD=64, CGN=8) -----------
// Two nodes per wave (32-lane halves); gather uses 8-deep predicated batch
// issue covering edges [0,32) in one shot (one exposed latency for deg<=32).
template <int F, int KTILES, int NTILES, int FOUT, int OSTR>
__global__ __launch_bounds__(256) void k_gcn_fused(
        const int* __restrict__ rowptr, const int* __restrict__ eSrc,
        const float* __restrict__ dinv, const f16* __restrict__ hs,
        const f16* __restrict__ Wb, const float* __restrict__ bias,
        f16* __restrict__ outh, int n) {
    constexpr int KPAD = KTILES * 32;   // 64 == input row stride RS
    constexpr int KP   = KPAD + 8;
    constexpr int CGN  = KPAD / 8;      // 8 f16x8 chunks per row
    constexpr int EPH  = 32 / CGN;      // 4 edge slots per half

    __shared__ __align__(16) f16 a_lds[64 * KP];

    int t = threadIdx.x;
    int node0 = blockIdx.x * 64;
    int w = t >> 6;
    int lane = t & 63;
    int half = lane >> 5;
    int l = lane & 31;
    int eslot = l / CGN;        // 0..3
    int cg = l & (CGN - 1);
    int ch0 = cg * 8;
    int lim = F - ch0;
    if (lim > 8) lim = 8;
    if (lim < 0) lim = 0;
    int lbase = half * 32;

    const f16x8* src = reinterpret_cast<const f16x8*>(hs);
    int nodeBase = node0 + w * 16;

    // ---- gather phase: 8 pair-steps, each half owns one node ----
    for (int i = 0; i < 8; i++) {
        int node = nodeBase + 2 * i + half;
        float acc[8];
#pragma unroll
        for (int j = 0; j < 8; j++) acc[j] = 0.f;
        float di = 0.f;

        if (node < n) {
            int rs_ = rowptr[node], re = rowptr[node + 1];
            di = dinv[node];
            int deg = re - rs_;
            int myidx = 0;
            if (l < deg) myidx = eSrc[rs_ + l];   // contiguous across halves

            // self term (edge-slot 0 of each half)
            if (eslot == 0) {
                f16x8 v = src[(long long)node * CGN + cg];
#pragma unroll
                for (int j = 0; j < 8; j++) acc[j] += (float)v[j];
            }

            int nfull = deg < 32 ? deg : 32;
            if (nfull > 0) {
                int sidx[8];
#pragma unroll
                for (int u = 0; u < 8; u++) {
                    int idx = u * EPH + eslot;
                    sidx[u] = __shfl(myidx, lbase + (idx < 31 ? idx : 31));
                }
                f16x8 v[8];
#pragma unroll
                for (int u = 0; u < 8; u++) {
                    int idx = u * EPH + eslot;
                    if (idx < nfull) v[u] = src[(long long)sidx[u] * CGN + cg];
                }
#pragma unroll
                for (int u = 0; u < 8; u++) {
                    int idx = u * EPH + eslot;
                    if (idx < nfull) {
#pragma unroll
                        for (int j = 0; j < 8; j++) acc[j] += (float)v[u][j];
                    }
                }
            }
            // overflow beyond 32 preloaded edges (P(deg>32) small)
            for (int e = rs_ + 32 + eslot; e < re; e += EPH) {
                int s = eSrc[e];
                f16x8 v = src[(long long)s * CGN + cg];
#pragma unroll
                for (int j = 0; j < 8; j++) acc[j] += (float)v[j];
            }

            // kill pad-channel garbage before the cross-slot reduce
#pragma unroll
            for (int j = 0; j < 8; j++)
                if (j >= lim) acc[j] = 0.f;
            // sum over edge-slot bits within the half (m = 8, 16)
#pragma unroll
            for (int m = CGN; m < 32; m <<= 1)
#pragma unroll
                for (int j = 0; j < 8; j++) acc[j] += __shfl_xor(acc[j], m);
        }

        if (eslot == 0) {
            f16x8 o;
#pragma unroll
            for (int j = 0; j < 8; j++) o[j] = (f16)(acc[j] * di);
            *reinterpret_cast<f16x8*>(&a_lds[(w * 16 + 2 * i + half) * KP + ch0]) = o;
        }
    }
    __syncthreads();

    // ---- MFMA phase ----
    int quad = lane >> 4;
    int col = lane & 15;

    f16x8 afr[KTILES];
#pragma unroll
    for (int kt = 0; kt < KTILES; kt++)
        afr[kt] = *reinterpret_cast<const f16x8*>(
            &a_lds[(16 * w + col) * KP + kt * 32 + quad * 8]);

    int nodeC = node0 + 16 * w + quad * 4;
    float dv[4];
#pragma unroll
    for (int r = 0; r < 4; r++) {
        int nd = nodeC + r;
        dv[r] = (nd < n) ? dinv[nd] : 0.f;
    }

    const f16x8* wb = reinterpret_cast<const f16x8*>(Wb);
#pragma unroll
    for (int nt = 0; nt < NTILES; nt++) {
        f16x8 bfr[KTILES];
#pragma unroll
        for (int kt = 0; kt < KTILES; kt++)
            bfr[kt] = wb[(nt * KTILES + kt) * 64 + lane];
        f32x4 acc = {0.f, 0.f, 0.f, 0.f};
#pragma unroll
        for (int kt = 0; kt < KTILES; kt++)
            acc = __builtin_amdgcn_mfma_f32_16x16x32_f16(afr[kt], bfr[kt], acc, 0, 0, 0);

        int ch = nt * 16 + col;
        if (ch < FOUT) {
            float bval = bias[ch];
#pragma unroll
            for (int r = 0; r < 4; r++) {
                int nd = nodeC + r;
                if (nd < n)
                    outh[(long long)nd * OSTR + ch] =
                        (f16)(fmaxf(acc[r] + bval, 0.f) * dv[r]);
            }
        }
    }
}

// ---- MFMA node GEMM with fused mean-pool (layer 3) -------------------------
template <int KTILES, int NTILES, int K, int FOUT>
__global__ __launch_bounds__(256) void k_gemm_pool(
        const f16* __restrict__ in, const f16* __restrict__ Wb,
        const float* __restrict__ bias, const int* __restrict__ batch,
        float* __restrict__ psum, int n) {
    constexpr int KPAD = KTILES * 32;
    constexpr int KP   = KPAD + 8;
    constexpr int V8   = KPAD / 8;
    constexpr int NSLOT = 4;

    __shared__ f16 a_lds[64 * KP];
    __shared__ float psum_l[NSLOT * FOUT];

    int t = threadIdx.x;
    int node0 = blockIdx.x * 64;

    const f16x8* inp = reinterpret_cast<const f16x8*>(in);
    for (int f = t; f < 64 * V8; f += 256) {
        int node = f / V8;
        int v = f - node * V8;
        f16x8 val = {};
        if (node0 + node < n) val = inp[(long long)(node0 + node) * V8 + v];
        *reinterpret_cast<f16x8*>(&a_lds[node * KP + v * 8]) = val;
    }
    for (int i = t; i < NSLOT * FOUT; i += 256) psum_l[i] = 0.f;
    __syncthreads();

    int w = t >> 6;
    int lane = t & 63;
    int quad = lane >> 4;
    int col = lane & 15;

    f16x8 afr[KTILES];
#pragma unroll
    for (int kt = 0; kt < KTILES; kt++)
        afr[kt] = *reinterpret_cast<const f16x8*>(
            &a_lds[(16 * w + col) * KP + kt * 32 + quad * 8]);

    int nodeC = node0 + 16 * w + quad * 4;
    int gb[4];
#pragma unroll
    for (int r = 0; r < 4; r++) {
        int nd = nodeC + r;
        gb[r] = (nd < n) ? batch[nd] : -1;
    }
    int g0 = batch[node0];

    const f16x8* wb = reinterpret_cast<const f16x8*>(Wb);
#pragma unroll
    for (int nt = 0; nt < NTILES; nt++) {
        f16x8 bfr[KTILES];
#pragma unroll
        for (int kt = 0; kt < KTILES; kt++)
            bfr[kt] = wb[(nt * KTILES + kt) * 64 + lane];
        f32x4 acc = {0.f, 0.f, 0.f, 0.f};
#pragma unroll
        for (int kt = 0; kt < KTILES; kt++)
            acc = __builtin_amdgcn_mfma_f32_16x16x32_f16(afr[kt], bfr[kt], acc, 0, 0, 0);

        int ch = nt * 16 + col;
        if (ch < FOUT) {
            float bval = bias[ch];
            if (gb[0] == gb[3] && gb[0] >= 0) {
                float s = fmaxf(acc[0] + bval, 0.f) + fmaxf(acc[1] + bval, 0.f)
                        + fmaxf(acc[2] + bval, 0.f) + fmaxf(acc[3] + bval, 0.f);
                int slot = gb[0] - g0;
                if (slot < NSLOT) atomicAdd(&psum_l[slot * FOUT + ch], s);
                else atomicAdd(&psum[gb[0] * FOUT + ch], s);
            } else {
#pragma unroll
                for (int r = 0; r < 4; r++) {
                    if (gb[r] < 0) continue;
                    float v = fmaxf(acc[r] + bval, 0.f);
                    int slot = gb[r] - g0;
                    if (slot < NSLOT) atomicAdd(&psum_l[slot * FOUT + ch], v);
                    else atomicAdd(&psum[gb[r] * FOUT + ch], v);
                }
            }
        }
    }

    __syncthreads();
    int lastNode = node0 + 63;
    if (lastNode >= n) lastNode = n - 1;
    int nsl = batch[lastNode] - g0 + 1;
    if (nsl > NSLOT) nsl = NSLOT;
    for (int f = t; f < nsl * FOUT; f += 256) {
        float v = psum_l[f];
        if (v != 0.f) atomicAdd(&psum[(g0 + f / FOUT) * FOUT + (f % FOUT)], v);
    }
}

// ---- FC layers (split; fc1 folds the mean divide) --------------------------
__global__ void k_fc1(const float* __restrict__ P, const int* __restrict__ start,
                      const float* __restrict__ W, const float* __restrict__ bias,
                      float* __restrict__ out) {
    int row = blockIdx.x >> 2;
    int o = (blockIdx.x & 3) * 256 + threadIdx.x;
    int cnt = start[row + 1] - start[row];
    float scale = 1.0f / fmaxf((float)cnt, 1.0f);
    __shared__ float prow[216];
    if (threadIdx.x < 216) prow[threadIdx.x] = P[row * 216 + threadIdx.x] * scale;
    __syncthreads();
    float acc = bias[o];
    for (int k = 0; k < 216; k++) acc += prow[k] * W[k * 1024 + o];
    out[row * 1024 + o] = fmaxf(acc, 0.f);
}
__global__ void k_fc2(const float* __restrict__ G, const float* __restrict__ W,
                      const float* __restrict__ bias, float* __restrict__ out) {
    int row = blockIdx.x;
    int o = threadIdx.x;  // 128
    __shared__ float grow[1024];
    for (int k = threadIdx.x; k < 1024; k += 128) grow[k] = G[row * 1024 + k];
    __syncthreads();
    float acc = bias[o];
    for (int k = 0; k < 1024; k++) acc += grow[k] * W[k * 128 + o];
    out[row * 128 + o] = acc;
}

// ---------------------------------------------------------------------------
extern "C" void kernel_launch(void* const* d_in, const int* in_sizes, int n_in,
                              void* d_out, int out_size, void* d_ws, size_t ws_size,
                              hipStream_t stream) {
    const float* x     = (const float*)d_in[0];
    const int*   ei    = (const int*)d_in[1];
    const int*   batch = (const int*)d_in[2];
    const float* W1  = (const float*)d_in[3];
    const float* b1  = (const float*)d_in[4];
    const float* W2  = (const float*)d_in[5];
    const float* b2  = (const float*)d_in[6];
    const float* W3  = (const float*)d_in[7];
    const float* b3  = (const float*)d_in[8];
    const float* Wf1 = (const float*)d_in[9];
    const float* bf1 = (const float*)d_in[10];
    const float* Wf2 = (const float*)d_in[11];
    const float* bf2 = (const float*)d_in[12];
    float* out = (float*)d_out;

    const int N = in_sizes[0] / 54;   // 100000 (< 2^17 for ebuf packing)
    const int E = in_sizes[1] / 2;    // 1600000
    const int G = 256;
    const int* row = ei;
    const int* col = ei + E;
    const int NB = cdiv(N, BSPAN);    // 196
    const int NBLK_A = cdiv(E, EPB);

    // workspace carve-up (256B aligned)
    char* ws = (char*)d_ws;
    size_t off = 0;
    auto carve = [&](size_t bytes) {
        void* p = ws + off;
        off += (bytes + 255) & ~(size_t)255;
        return p;
    };
    int*   rowptr  = (int*)carve((size_t)(N + 1) * 4);
    int*   bktCnt  = (int*)carve(256 * 4);
    int*   bktCur  = (int*)carve(256 * 4);
    int*   eSrc    = (int*)carve((size_t)E * 4);
    float* dinv    = (float*)carve((size_t)N * 4);
    f16*   xs      = (f16*)carve((size_t)N * 64 * 2);    // F=54 padded to 64
    f16*   hsbuf   = (f16*)carve((size_t)N * 128 * 2);   // ping (stride 64 or 128)
    f16*   bufA    = (f16*)carve((size_t)N * 128 * 2);   // pong
    unsigned int* ebuf = (unsigned int*)carve((size_t)E * 4);
    float* psum    = (float*)carve((size_t)G * 216 * 4);
    float* gbuf    = (float*)carve((size_t)G * 1024 * 4);
    int*   start   = (int*)carve((size_t)(G + 1) * 4);
    f16*   w1b     = (f16*)carve((size_t)4 * 2 * 512 * 2);
    f16*   w2b     = (f16*)carve((size_t)7 * 2 * 512 * 2);
    f16*   w3b     = (f16*)carve((size_t)14 * 4 * 512 * 2);

    const int T = 256;
    // note: bktCnt must start at 0; k_init zeroes bktCur but accumulates into
    // bktCnt via atomics, so zero bktCnt with a tiny prefix inside k_init is
    // racy across blocks -> use hipMemsetAsync (allowed, stream op).
    hipMemsetAsync(bktCnt, 0, 256 * 4, stream);

    // ---- combined init (zero + weight pack + boundaries + bucket hist) ----
    int gInit = cdiv(N, T) > NBLK_A ? cdiv(N, T) : NBLK_A;
    k_init<<<gInit, T, 0, stream>>>(batch, start, psum, bktCnt, bktCur, col,
                                    W1, W2, W3, w1b, w2b, w3b, E, NB, N, G);

    // ---- bucketed CSR build: part -> build(+prescale) ----
    k_bkt_part<<<NBLK_A, 256, 0, stream>>>(row, col, bktCnt, bktCur, ebuf, E, NB);
    k_bkt_build<<<NB, 256, 0, stream>>>(ebuf, bktCnt, rowptr, dinv, eSrc, x, xs, N, NB);

    const int GB = cdiv(N, 64);

    // ---- layer 1 (fused): xs -> hsbuf (54ch, stride 64) ----
    k_gcn_fused<54, 2, 4, 54, 64><<<GB, 256, 0, stream>>>(
        rowptr, eSrc, dinv, xs, w1b, b1, hsbuf, N);

    // ---- layer 2 (fused): hsbuf -> bufA (108ch, stride 128) ----
    k_gcn_fused<54, 2, 7, 108, 128><<<GB, 256, 0, stream>>>(
        rowptr, eSrc, dinv, hsbuf, w2b, b2, bufA, N);

    // ---- layer 3 (split): gather108 bufA -> hsbuf, then GEMM+pool ----
    k_gatherw<108, 128><<<cdiv(N, 4), 256, 0, stream>>>(rowptr, eSrc, dinv, bufA, hsbuf, N);
    k_gemm_pool<4, 14, 108, 216><<<GB, 256, 0, stream>>>(
        hsbuf, w3b, b3, batch, psum, N);

    // ---- FC head (split) ----
    k_fc1<<<G * 4, T, 0, stream>>>(psum, start, Wf1, bf1, gbuf);
    k_fc2<<<G, 128, 0, stream>>>(gbuf, Wf2, bf2, out);
}

// Round 9
// 383.332 us; speedup vs baseline: 1.0413x; 1.0413x over previous
//
#include <hip/hip_runtime.h>

// ---------------------------------------------------------------------------
// ProteinGCNNet: 3x GCNConv + mean-pool + 2 FC layers.
// Round 24 (= R23 resubmit; prior bench died to container infra failure).
// (1) R22's prescale-into-bkt_build fusion reverted (serialized a full-grid
// pass into 196 blocks: +15us). Standalone k_prescale restored.
// (2) Fused gather+GEMM kernels at 512 threads (8 waves): each wave owns an
// 8-node strip (2 nodes concurrently via 32-lane halves) -> gather-phase
// critical path 8 steps -> 4. MFMA phase splits NT tiles across wave pairs
// (A-fragments shared via LDS, channel-disjoint outputs). Same 64-node tile,
// same 9KB LDS. k_init+hist fusion and 8-deep predicated gathers kept.
// ---------------------------------------------------------------------------

typedef _Float16 f16;
typedef _Float16 f16x2 __attribute__((ext_vector_type(2)));
typedef _Float16 f16x8 __attribute__((ext_vector_type(8)));
typedef float f32x4 __attribute__((ext_vector_type(4)));

static __host__ __device__ inline int cdiv(int a, int b) { return (a + b - 1) / b; }

constexpr int BSPAN = 512;
constexpr int EPB   = 4096;
constexpr int EPT   = EPB / 256;

// ---- MFMA weight pack helper ----------------------------------------------
__device__ __forceinline__ void wpack_one(const float* W, f16* Wb, int K, int F,
                                          int KT, int idx) {
    int j = idx & 7;
    int lane = (idx >> 3) & 63;
    int fi = idx >> 9;
    int kt = fi % KT;
    int nt = fi / KT;
    int k = kt * 32 + (lane >> 4) * 8 + j;
    int nn = nt * 16 + (lane & 15);
    Wb[idx] = (k < K && nn < F) ? (f16)W[k * F + nn] : (f16)0.f;
}

// ---- combined init: zero + weight pack + boundaries + bucket histogram -----
__global__ __launch_bounds__(256) void k_init(
        const int* __restrict__ batch, int* __restrict__ start,
        float* __restrict__ psum, int* __restrict__ bktCnt, int* __restrict__ bktCur,
        const int* __restrict__ col,
        const float* __restrict__ W1, const float* __restrict__ W2,
        const float* __restrict__ W3, f16* __restrict__ w1b,
        f16* __restrict__ w2b, f16* __restrict__ w3b,
        int e, int nb, int n, int g) {
    __shared__ int hist[256];
    int t = threadIdx.x;
    int i = blockIdx.x * blockDim.x + t;
    hist[t] = 0;
    __syncthreads();
    int ebase = blockIdx.x * EPB;
#pragma unroll
    for (int j = 0; j < EPT; j++) {
        int idx = ebase + j * 256 + t;
        if (idx < e) atomicAdd(&hist[col[idx] >> 9], 1);
    }
    if (i < g * 216) psum[i] = 0.f;
    if (i < 256) bktCur[i] = 0;
    constexpr int T1 = 4 * 2 * 512;
    constexpr int T2 = 7 * 2 * 512;
    constexpr int T3 = 14 * 4 * 512;
    if (i < T1) wpack_one(W1, w1b, 54, 54, 2, i);
    else if (i < T1 + T2) wpack_one(W2, w2b, 54, 108, 2, i - T1);
    else if (i < T1 + T2 + T3) wpack_one(W3, w3b, 108, 216, 4, i - T1 - T2);
    if (i < n) {
        int b = batch[i];
        int bp = (i == 0) ? -1 : batch[i - 1];
        for (int gg = bp + 1; gg <= b; gg++) start[gg] = i;
        if (i == n - 1)
            for (int gg = b + 1; gg <= g; gg++) start[gg] = n;
    }
    __syncthreads();
    if (t < nb && hist[t] > 0) atomicAdd(&bktCnt[t], hist[t]);
}

// ---- in-block exclusive scan ------------------------------------------------
__device__ __forceinline__ int scan256_ex(int* sbuf, int v, int t) {
    sbuf[t] = v;
    __syncthreads();
    for (int off = 1; off < 256; off <<= 1) {
        int x = sbuf[t];
        int y = (t >= off) ? sbuf[t - off] : 0;
        __syncthreads();
        sbuf[t] = x + y;
        __syncthreads();
    }
    return sbuf[t] - v;
}

// ---- A2: partition edges; ebuf packed (ldst<<17)|src (N < 2^17) ------------
__global__ __launch_bounds__(256) void k_bkt_part(const int* __restrict__ row,
                                                  const int* __restrict__ col,
                                                  const int* __restrict__ bktCnt,
                                                  int* bktCur, unsigned int* __restrict__ ebuf,
                                                  int e, int nb) {
    __shared__ int sbuf[256];
    __shared__ int hist[256];
    __shared__ int base[256];
    __shared__ int lcur[256];
    int t = threadIdx.x;
    int boff = scan256_ex(sbuf, (t < nb) ? bktCnt[t] : 0, t);
    hist[t] = 0; lcur[t] = 0;
    __syncthreads();
    int bs = blockIdx.x * EPB;
    unsigned int pk[EPT];
    int b[EPT];
#pragma unroll
    for (int j = 0; j < EPT; j++) {
        int idx = bs + j * 256 + t;
        if (idx < e) {
            int c = col[idx];
            pk[j] = ((unsigned int)(c & (BSPAN - 1)) << 17) | (unsigned int)row[idx];
            b[j] = c >> 9;
            atomicAdd(&hist[b[j]], 1);
        } else b[j] = -1;
    }
    __syncthreads();
    if (t < nb && hist[t] > 0) base[t] = boff + atomicAdd(&bktCur[t], hist[t]);
    __syncthreads();
#pragma unroll
    for (int j = 0; j < EPT; j++) {
        if (b[j] >= 0) {
            int lofs = atomicAdd(&lcur[b[j]], 1);
            ebuf[base[b[j]] + lofs] = pk[j];
        }
    }
}

// ---- B: per-bucket hist+scan -> rowptr + dinv + CSR fill -------------------
__global__ __launch_bounds__(256) void k_bkt_build(const unsigned int* __restrict__ ebuf,
                                                   const int* __restrict__ bktCnt,
                                                   int* __restrict__ rowptr,
                                                   float* __restrict__ dinv,
                                                   int* __restrict__ eSrc,
                                                   int n, int nb) {
    __shared__ int sbuf[256];
    __shared__ int hist[BSPAN];
    __shared__ int cur[BSPAN];
    int t = threadIdx.x;
    int bkt = blockIdx.x;

    int boff_ex = scan256_ex(sbuf, (t < nb) ? bktCnt[t] : 0, t);
    __shared__ int boff_s, cnt_s;
    if (t == bkt) boff_s = boff_ex;
    if (t == 0) cnt_s = bktCnt[bkt];
    hist[t] = 0; hist[t + 256] = 0;
    __syncthreads();
    int es = boff_s, ee = boff_s + cnt_s;

    {
        int i = es + t;
        for (; i + 3 * 256 < ee; i += 4 * 256) {
            unsigned p0 = ebuf[i], p1 = ebuf[i + 256], p2 = ebuf[i + 512], p3 = ebuf[i + 768];
            atomicAdd(&hist[p0 >> 17], 1);
            atomicAdd(&hist[p1 >> 17], 1);
            atomicAdd(&hist[p2 >> 17], 1);
            atomicAdd(&hist[p3 >> 17], 1);
        }
        for (; i < ee; i += 256) atomicAdd(&hist[ebuf[i] >> 17], 1);
    }
    __syncthreads();

    int h0 = hist[2 * t], h1 = hist[2 * t + 1];
    __syncthreads();
    int ex = scan256_ex(sbuf, h0 + h1, t);
    int e0 = es + ex, e1 = e0 + h0;

    int node0 = bkt * BSPAN;
    int n0 = node0 + 2 * t, n1 = node0 + 2 * t + 1;
    if (n0 <= n) rowptr[n0] = e0;
    if (n1 <= n) rowptr[n1] = e1;
    if (n0 < n) dinv[n0] = rsqrtf((float)(h0 + 1));
    if (n1 < n) dinv[n1] = rsqrtf((float)(h1 + 1));
    cur[2 * t] = e0; cur[2 * t + 1] = e1;
    __syncthreads();

    {
        int i = es + t;
        for (; i + 3 * 256 < ee; i += 4 * 256) {
            unsigned p0 = ebuf[i], p1 = ebuf[i + 256], p2 = ebuf[i + 512], p3 = ebuf[i + 768];
            int s0 = atomicAdd(&cur[p0 >> 17], 1);
            int s1 = atomicAdd(&cur[p1 >> 17], 1);
            int s2 = atomicAdd(&cur[p2 >> 17], 1);
            int s3 = atomicAdd(&cur[p3 >> 17], 1);
            eSrc[s0] = (int)(p0 & 0x1FFFFu);
            eSrc[s1] = (int)(p1 & 0x1FFFFu);
            eSrc[s2] = (int)(p2 & 0x1FFFFu);
            eSrc[s3] = (int)(p3 & 0x1FFFFu);
        }
        for (; i < ee; i += 256) {
            unsigned int p = ebuf[i];
            int slot = atomicAdd(&cur[p >> 17], 1);
            eSrc[slot] = (int)(p & 0x1FFFFu);
        }
    }
}

// ---- xs = f16(dinv (x) x), padded row stride RS (standalone, full grid) ----
template <int F, int RS>
__global__ void k_prescale(const float* __restrict__ x, const float* __restrict__ dinv,
                           f16* __restrict__ xs, int n) {
    constexpr int CH = F / 2;
    int idx = blockIdx.x * blockDim.x + threadIdx.x;
    if (idx >= n * CH) return;
    int node = idx / CH;
    int c = idx - node * CH;
    float d = dinv[node];
    float2 v = *reinterpret_cast<const float2*>(x + (long long)node * F + c * 2);
    f16x2 h;
    h[0] = (f16)(v.x * d);
    h[1] = (f16)(v.y * d);
    *reinterpret_cast<f16x2*>(xs + (long long)node * RS + c * 2) = h;
}

// ---- wide gather, 8-deep predicated batch issue (standalone, layer 3) ------
template <int F, int RS>
__global__ __launch_bounds__(256) void k_gatherw(
        const int* __restrict__ rowptr, const int* __restrict__ eSrc,
        const float* __restrict__ dinv, const f16* __restrict__ hs,
        f16* __restrict__ out, int n) {
    constexpr int CGN = RS / 8;    // f16x8 chunks per row (16 for RS=128)
    constexpr int EPW = 64 / CGN;  // rows gathered per wave instr (4)
    int wave = threadIdx.x >> 6;
    int lane = threadIdx.x & 63;
    int eslot = lane / CGN;
    int cg = lane & (CGN - 1);
    int node = blockIdx.x * 4 + wave;
    if (node >= n) return;
    int ch0 = cg * 8;
    int lim = F - ch0;
    if (lim > 8) lim = 8;
    if (lim < 0) lim = 0;

    int rs_ = rowptr[node], re = rowptr[node + 1];
    float di = dinv[node];
    int deg = re - rs_;
    int myidx = 0;
    if (lane < deg) myidx = eSrc[rs_ + lane];

    const f16x8* src = reinterpret_cast<const f16x8*>(hs);
    float acc[8];
#pragma unroll
    for (int j = 0; j < 8; j++) acc[j] = 0.f;

    if (eslot == 0) {
        f16x8 v = src[(long long)node * CGN + cg];
#pragma unroll
        for (int j = 0; j < 8; j++) acc[j] += (float)v[j];
    }

    int nfull = deg < 64 ? deg : 64;
    for (int base = 0; base < nfull; base += 8 * EPW) {
        int sidx[8];
#pragma unroll
        for (int u = 0; u < 8; u++) {
            int idx = base + u * EPW + eslot;
            sidx[u] = __shfl(myidx, idx < 63 ? idx : 63);
        }
        f16x8 v[8];
#pragma unroll
        for (int u = 0; u < 8; u++) {
            int idx = base + u * EPW + eslot;
            if (idx < nfull) v[u] = src[(long long)sidx[u] * CGN + cg];
        }
#pragma unroll
        for (int u = 0; u < 8; u++) {
            int idx = base + u * EPW + eslot;
            if (idx < nfull) {
#pragma unroll
                for (int j = 0; j < 8; j++) acc[j] += (float)v[u][j];
            }
        }
    }
    for (int e = rs_ + 64 + eslot; e < re; e += EPW) {
        int s = eSrc[e];
        f16x8 v = src[(long long)s * CGN + cg];
#pragma unroll
        for (int j = 0; j < 8; j++) acc[j] += (float)v[j];
    }

#pragma unroll
    for (int j = 0; j < 8; j++)
        if (j >= lim) acc[j] = 0.f;
#pragma unroll
    for (int m = CGN; m < 64; m <<= 1)
#pragma unroll
        for (int j = 0; j < 8; j++) acc[j] += __shfl_xor(acc[j], m);

    if (eslot == 0) {
        f16x8 o;
#pragma unroll
        for (int j = 0; j < 8; j++) o[j] = (f16)(acc[j] * di);
        *reinterpret_cast<f16x8*>(out + (long long)node * RS + ch0) = o;
    }
}

// ---- fused gather + MFMA GEMM, 8 waves (layers 1/2: F=54, KPAD=64) ---------
// Gather: wave w owns an 8-node strip, 2 nodes concurrent (32-lane halves),
// 4 serial pair-steps; 8-deep predicated batch covers edges [0,32) in one
// issue burst. MFMA: wave pairs split the NT tiles (A shared via LDS).
template <int F, int KTILES, int NTILES, int FOUT, int OSTR>
__global__ __launch_bounds__(512) void k_gcn_fused(
        const int* __restrict__ rowptr, const int* __restrict__ eSrc,
        const float* __restrict__ dinv, const f16* __restrict__ hs,
        const f16* __restrict__ Wb, const float* __restrict__ bias,
        f16* __restrict__ outh, int n) {
    constexpr int KPAD = KTILES * 32;   // 64 == input row stride RS
    constexpr int KP   = KPAD + 8;
    constexpr int CGN  = KPAD / 8;      // 8 f16x8 chunks per row
    constexpr int EPH  = 32 / CGN;      // 4 edge slots per half
    constexpr int NT0  = (NTILES + 1) / 2;

    __shared__ __align__(16) f16 a_lds[64 * KP];

    int t = threadIdx.x;
    int node0 = blockIdx.x * 64;
    int w = t >> 6;             // 0..7
    int lane = t & 63;
    int half = lane >> 5;
    int l = lane & 31;
    int eslot = l / CGN;        // 0..3
    int cg = l & (CGN - 1);
    int ch0 = cg * 8;
    int lim = F - ch0;
    if (lim > 8) lim = 8;
    if (lim < 0) lim = 0;
    int lbase = half * 32;

    const f16x8* src = reinterpret_cast<const f16x8*>(hs);
    int nodeBase = node0 + w * 8;

    // ---- gather phase: 4 pair-steps, each half owns one node ----
    for (int i = 0; i < 4; i++) {
        int node = nodeBase + 2 * i + half;
        float acc[8];
#pragma unroll
        for (int j = 0; j < 8; j++) acc[j] = 0.f;
        float di = 0.f;

        if (node < n) {
            int rs_ = rowptr[node], re = rowptr[node + 1];
            di = dinv[node];
            int deg = re - rs_;
            int myidx = 0;
            if (l < deg) myidx = eSrc[rs_ + l];   // contiguous across halves

            if (eslot == 0) {
                f16x8 v = src[(long long)node * CGN + cg];
#pragma unroll
                for (int j = 0; j < 8; j++) acc[j] += (float)v[j];
            }

            int nfull = deg < 32 ? deg : 32;
            if (nfull > 0) {
                int sidx[8];
#pragma unroll
                for (int u = 0; u < 8; u++) {
                    int idx = u * EPH + eslot;
                    sidx[u] = __shfl(myidx, lbase + (idx < 31 ? idx : 31));
                }
                f16x8 v[8];
#pragma unroll
                for (int u = 0; u < 8; u++) {
                    int idx = u * EPH + eslot;
                    if (idx < nfull) v[u] = src[(long long)sidx[u] * CGN + cg];
                }
#pragma unroll
                for (int u = 0; u < 8; u++) {
                    int idx = u * EPH + eslot;
                    if (idx < nfull) {
#pragma unroll
                        for (int j = 0; j < 8; j++) acc[j] += (float)v[u][j];
                    }
                }
            }
            // overflow beyond 32 preloaded edges (P(deg>32) small)
            for (int e = rs_ + 32 + eslot; e < re; e += EPH) {
                int s = eSrc[e];
                f16x8 v = src[(long long)s * CGN + cg];
#pragma unroll
                for (int j = 0; j < 8; j++) acc[j] += (float)v[j];
            }

#pragma unroll
            for (int j = 0; j < 8; j++)
                if (j >= lim) acc[j] = 0.f;
#pragma unroll
            for (int m = CGN; m < 32; m <<= 1)
#pragma unroll
                for (int j = 0; j < 8; j++) acc[j] += __shfl_xor(acc[j], m);
        }

        if (eslot == 0) {
            f16x8 o;
#pragma unroll
            for (int j = 0; j < 8; j++) o[j] = (f16)(acc[j] * di);
            *reinterpret_cast<f16x8*>(&a_lds[(w * 8 + 2 * i + half) * KP + ch0]) = o;
        }
    }
    __syncthreads();

    // ---- MFMA phase: wave pairs split NT tiles ----
    int rw = w & 3;             // row group (16 nodes)
    int ng = w >> 2;            // NT half
    int quad = lane >> 4;
    int col = lane & 15;

    f16x8 afr[KTILES];
#pragma unroll
    for (int kt = 0; kt < KTILES; kt++)
        afr[kt] = *reinterpret_cast<const f16x8*>(
            &a_lds[(16 * rw + col) * KP + kt * 32 + quad * 8]);

    int nodeC = node0 + 16 * rw + quad * 4;
    float dv[4];
#pragma unroll
    for (int r = 0; r < 4; r++) {
        int nd = nodeC + r;
        dv[r] = (nd < n) ? dinv[nd] : 0.f;
    }

    const f16x8* wb = reinterpret_cast<const f16x8*>(Wb);
#pragma unroll
    for (int nt = 0; nt < NTILES; nt++) {
        if ((nt < NT0) != (ng == 0)) continue;
        f16x8 bfr[KTILES];
#pragma unroll
        for (int kt = 0; kt < KTILES; kt++)
            bfr[kt] = wb[(nt * KTILES + kt) * 64 + lane];
        f32x4 acc = {0.f, 0.f, 0.f, 0.f};
#pragma unroll
        for (int kt = 0; kt < KTILES; kt++)
            acc = __builtin_amdgcn_mfma_f32_16x16x32_f16(afr[kt], bfr[kt], acc, 0, 0, 0);

        int ch = nt * 16 + col;
        if (ch < FOUT) {
            float bval = bias[ch];
#pragma unroll
            for (int r = 0; r < 4; r++) {
                int nd = nodeC + r;
                if (nd < n)
                    outh[(long long)nd * OSTR + ch] =
                        (f16)(fmaxf(acc[r] + bval, 0.f) * dv[r]);
            }
        }
    }
}

// ---- MFMA node GEMM with fused mean-pool (layer 3) -------------------------
template <int KTILES, int NTILES, int K, int FOUT>
__global__ __launch_bounds__(256) void k_gemm_pool(
        const f16* __restrict__ in, const f16* __restrict__ Wb,
        const float* __restrict__ bias, const int* __restrict__ batch,
        float* __restrict__ psum, int n) {
    constexpr int KPAD = KTILES * 32;
    constexpr int KP   = KPAD + 8;
    constexpr int V8   = KPAD / 8;
    constexpr int NSLOT = 4;

    __shared__ f16 a_lds[64 * KP];
    __shared__ float psum_l[NSLOT * FOUT];

    int t = threadIdx.x;
    int node0 = blockIdx.x * 64;

    const f16x8* inp = reinterpret_cast<const f16x8*>(in);
    for (int f = t; f < 64 * V8; f += 256) {
        int node = f / V8;
        int v = f - node * V8;
        f16x8 val = {};
        if (node0 + node < n) val = inp[(long long)(node0 + node) * V8 + v];
        *reinterpret_cast<f16x8*>(&a_lds[node * KP + v * 8]) = val;
    }
    for (int i = t; i < NSLOT * FOUT; i += 256) psum_l[i] = 0.f;
    __syncthreads();

    int w = t >> 6;
    int lane = t & 63;
    int quad = lane >> 4;
    int col = lane & 15;

    f16x8 afr[KTILES];
#pragma unroll
    for (int kt = 0; kt < KTILES; kt++)
        afr[kt] = *reinterpret_cast<const f16x8*>(
            &a_lds[(16 * w + col) * KP + kt * 32 + quad * 8]);

    int nodeC = node0 + 16 * w + quad * 4;
    int gb[4];
#pragma unroll
    for (int r = 0; r < 4; r++) {
        int nd = nodeC + r;
        gb[r] = (nd < n) ? batch[nd] : -1;
    }
    int g0 = batch[node0];

    const f16x8* wb = reinterpret_cast<const f16x8*>(Wb);
#pragma unroll
    for (int nt = 0; nt < NTILES; nt++) {
        f16x8 bfr[KTILES];
#pragma unroll
        for (int kt = 0; kt < KTILES; kt++)
            bfr[kt] = wb[(nt * KTILES + kt) * 64 + lane];
        f32x4 acc = {0.f, 0.f, 0.f, 0.f};
#pragma unroll
        for (int kt = 0; kt < KTILES; kt++)
            acc = __builtin_amdgcn_mfma_f32_16x16x32_f16(afr[kt], bfr[kt], acc, 0, 0, 0);

        int ch = nt * 16 + col;
        if (ch < FOUT) {
            float bval = bias[ch];
            if (gb[0] == gb[3] && gb[0] >= 0) {
                float s = fmaxf(acc[0] + bval, 0.f) + fmaxf(acc[1] + bval, 0.f)
                        + fmaxf(acc[2] + bval, 0.f) + fmaxf(acc[3] + bval, 0.f);
                int slot = gb[0] - g0;
                if (slot < NSLOT) atomicAdd(&psum_l[slot * FOUT + ch], s);
                else atomicAdd(&psum[gb[0] * FOUT + ch], s);
            } else {
#pragma unroll
                for (int r = 0; r < 4; r++) {
                    if (gb[r] < 0) continue;
                    float v = fmaxf(acc[r] + bval, 0.f);
                    int slot = gb[r] - g0;
                    if (slot < NSLOT) atomicAdd(&psum_l[slot * FOUT + ch], v);
                    else atomicAdd(&psum[gb[r] * FOUT + ch], v);
                }
            }
        }
    }

    __syncthreads();
    int lastNode = node0 + 63;
    if (lastNode >= n) lastNode = n - 1;
    int nsl = batch[lastNode] - g0 + 1;
    if (nsl > NSLOT) nsl = NSLOT;
    for (int f = t; f < nsl * FOUT; f += 256) {
        float v = psum_l[f];
        if (v != 0.f) atomicAdd(&psum[(g0 + f / FOUT) * FOUT + (f % FOUT)], v);
    }
}

// ---- FC layers (split; fc1 folds the mean divide) --------------------------
__global__ void k_fc1(const float* __restrict__ P, const int* __restrict__ start,
                      const float* __restrict__ W, const float* __restrict__ bias,
                      float* __restrict__ out) {
    int row = blockIdx.x >> 2;
    int o = (blockIdx.x & 3) * 256 + threadIdx.x;
    int cnt = start[row + 1] - start[row];
    float scale = 1.0f / fmaxf((float)cnt, 1.0f);
    __shared__ float prow[216];
    if (threadIdx.x < 216) prow[threadIdx.x] = P[row * 216 + threadIdx.x] * scale;
    __syncthreads();
    float acc = bias[o];
    for (int k = 0; k < 216; k++) acc += prow[k] * W[k * 1024 + o];
    out[row * 1024 + o] = fmaxf(acc, 0.f);
}
__global__ void k_fc2(const float* __restrict__ G, const float* __restrict__ W,
                      const float* __restrict__ bias, float* __restrict__ out) {
    int row = blockIdx.x;
    int o = threadIdx.x;  // 128
    __shared__ float grow[1024];
    for (int k = threadIdx.x; k < 1024; k += 128) grow[k] = G[row * 1024 + k];
    __syncthreads();
    float acc = bias[o];
    for (int k = 0; k < 1024; k++) acc += grow[k] * W[k * 128 + o];
    out[row * 128 + o] = acc;
}

// ---------------------------------------------------------------------------
extern "C" void kernel_launch(void* const* d_in, const int* in_sizes, int n_in,
                              void* d_out, int out_size, void* d_ws, size_t ws_size,
                              hipStream_t stream) {
    const float* x     = (const float*)d_in[0];
    const int*   ei    = (const int*)d_in[1];
    const int*   batch = (const int*)d_in[2];
    const float* W1  = (const float*)d_in[3];
    const float* b1  = (const float*)d_in[4];
    const float* W2  = (const float*)d_in[5];
    const float* b2  = (const float*)d_in[6];
    const float* W3  = (const float*)d_in[7];
    const float* b3  = (const float*)d_in[8];
    const float* Wf1 = (const float*)d_in[9];
    const float* bf1 = (const float*)d_in[10];
    const float* Wf2 = (const float*)d_in[11];
    const float* bf2 = (const float*)d_in[12];
    float* out = (float*)d_out;

    const int N = in_sizes[0] / 54;   // 100000 (< 2^17 for ebuf packing)
    const int E = in_sizes[1] / 2;    // 1600000
    const int G = 256;
    const int* row = ei;
    const int* col = ei + E;
    const int NB = cdiv(N, BSPAN);    // 196
    const int NBLK_A = cdiv(E, EPB);

    // workspace carve-up (256B aligned)
    char* ws = (char*)d_ws;
    size_t off = 0;
    auto carve = [&](size_t bytes) {
        void* p = ws + off;
        off += (bytes + 255) & ~(size_t)255;
        return p;
    };
    int*   rowptr  = (int*)carve((size_t)(N + 1) * 4);
    int*   bktCnt  = (int*)carve(256 * 4);
    int*   bktCur  = (int*)carve(256 * 4);
    int*   eSrc    = (int*)carve((size_t)E * 4);
    float* dinv    = (float*)carve((size_t)N * 4);
    f16*   xs      = (f16*)carve((size_t)N * 64 * 2);    // F=54 padded to 64
    f16*   hsbuf   = (f16*)carve((size_t)N * 128 * 2);   // ping (stride 64 or 128)
    f16*   bufA    = (f16*)carve((size_t)N * 128 * 2);   // pong
    unsigned int* ebuf = (unsigned int*)carve((size_t)E * 4);
    float* psum    = (float*)carve((size_t)G * 216 * 4);
    float* gbuf    = (float*)carve((size_t)G * 1024 * 4);
    int*   start   = (int*)carve((size_t)(G + 1) * 4);
    f16*   w1b     = (f16*)carve((size_t)4 * 2 * 512 * 2);
    f16*   w2b     = (f16*)carve((size_t)7 * 2 * 512 * 2);
    f16*   w3b     = (f16*)carve((size_t)14 * 4 * 512 * 2);

    const int T = 256;
    // bktCnt must be zero before k_init's cross-block atomic accumulation
    hipMemsetAsync(bktCnt, 0, 256 * 4, stream);

    // ---- combined init (zero + weight pack + boundaries + bucket hist) ----
    int gInit = cdiv(N, T) > NBLK_A ? cdiv(N, T) : NBLK_A;
    k_init<<<gInit, T, 0, stream>>>(batch, start, psum, bktCnt, bktCur, col,
                                    W1, W2, W3, w1b, w2b, w3b, E, NB, N, G);

    // ---- bucketed CSR build: part -> build ----
    k_bkt_part<<<NBLK_A, 256, 0, stream>>>(row, col, bktCnt, bktCur, ebuf, E, NB);
    k_bkt_build<<<NB, 256, 0, stream>>>(ebuf, bktCnt, rowptr, dinv, eSrc, N, NB);

    // ---- prescale (standalone, full grid) ----
    k_prescale<54, 64><<<cdiv(N * 27, T), T, 0, stream>>>(x, dinv, xs, N);

    const int GB = cdiv(N, 64);

    // ---- layer 1 (fused, 8 waves): xs -> hsbuf (54ch, stride 64) ----
    k_gcn_fused<54, 2, 4, 54, 64><<<GB, 512, 0, stream>>>(
        rowptr, eSrc, dinv, xs, w1b, b1, hsbuf, N);

    // ---- layer 2 (fused, 8 waves): hsbuf -> bufA (108ch, stride 128) ----
    k_gcn_fused<54, 2, 7, 108, 128><<<GB, 512, 0, stream>>>(
        rowptr, eSrc, dinv, hsbuf, w2b, b2, bufA, N);

    // ---- layer 3 (split): gather108 bufA -> hsbuf, then GEMM+pool ----
    k_gatherw<108, 128><<<cdiv(N, 4), 256, 0, stream>>>(rowptr, eSrc, dinv, bufA, hsbuf, N);
    k_gemm_pool<4, 14, 108, 216><<<GB, 256, 0, stream>>>(
        hsbuf, w3b, b3, batch, psum, N);

    // ---- FC head (split) ----
    k_fc1<<<G * 4, T, 0, stream>>>(psum, start, Wf1, bf1, gbuf);
    k_fc2<<<G, 128, 0, stream>>>(gbuf, Wf2, bf2, out);
}

// Round 10
// 379.619 us; speedup vs baseline: 1.0515x; 1.0098x over previous
//
#include <hip/hip_runtime.h>

// ---------------------------------------------------------------------------
// ProteinGCNNet: 3x GCNConv + mean-pool + 2 FC layers.
// Round 25: recombine the best pieces. R24 showed 512-thread fused kernels
// REGRESS (L2 59->70us, bank conflicts 2x, no occupancy gain) while its other
// changes (k_init+hist fusion, 8-deep predicated gathers, fewer launches)
// saved ~14us. So: R24 base with k_gcn_fused reverted to 256 threads / 4
// waves / two-nodes-per-wave (R21 shape + 8-deep predicated batch issue).
// L3 split (gatherw at its 190MB traffic floor), bucketed CSR, MFMA GEMMs,
// fused pool, split FC head kept.
// ---------------------------------------------------------------------------

typedef _Float16 f16;
typedef _Float16 f16x2 __attribute__((ext_vector_type(2)));
typedef _Float16 f16x8 __attribute__((ext_vector_type(8)));
typedef float f32x4 __attribute__((ext_vector_type(4)));

static __host__ __device__ inline int cdiv(int a, int b) { return (a + b - 1) / b; }

constexpr int BSPAN = 512;
constexpr int EPB   = 4096;
constexpr int EPT   = EPB / 256;

// ---- MFMA weight pack helper ----------------------------------------------
__device__ __forceinline__ void wpack_one(const float* W, f16* Wb, int K, int F,
                                          int KT, int idx) {
    int j = idx & 7;
    int lane = (idx >> 3) & 63;
    int fi = idx >> 9;
    int kt = fi % KT;
    int nt = fi / KT;
    int k = kt * 32 + (lane >> 4) * 8 + j;
    int nn = nt * 16 + (lane & 15);
    Wb[idx] = (k < K && nn < F) ? (f16)W[k * F + nn] : (f16)0.f;
}

// ---- combined init: zero + weight pack + boundaries + bucket histogram -----
__global__ __launch_bounds__(256) void k_init(
        const int* __restrict__ batch, int* __restrict__ start,
        float* __restrict__ psum, int* __restrict__ bktCnt, int* __restrict__ bktCur,
        const int* __restrict__ col,
        const float* __restrict__ W1, const float* __restrict__ W2,
        const float* __restrict__ W3, f16* __restrict__ w1b,
        f16* __restrict__ w2b, f16* __restrict__ w3b,
        int e, int nb, int n, int g) {
    __shared__ int hist[256];
    int t = threadIdx.x;
    int i = blockIdx.x * blockDim.x + t;
    hist[t] = 0;
    __syncthreads();
    int ebase = blockIdx.x * EPB;
#pragma unroll
    for (int j = 0; j < EPT; j++) {
        int idx = ebase + j * 256 + t;
        if (idx < e) atomicAdd(&hist[col[idx] >> 9], 1);
    }
    if (i < g * 216) psum[i] = 0.f;
    if (i < 256) bktCur[i] = 0;
    constexpr int T1 = 4 * 2 * 512;
    constexpr int T2 = 7 * 2 * 512;
    constexpr int T3 = 14 * 4 * 512;
    if (i < T1) wpack_one(W1, w1b, 54, 54, 2, i);
    else if (i < T1 + T2) wpack_one(W2, w2b, 54, 108, 2, i - T1);
    else if (i < T1 + T2 + T3) wpack_one(W3, w3b, 108, 216, 4, i - T1 - T2);
    if (i < n) {
        int b = batch[i];
        int bp = (i == 0) ? -1 : batch[i - 1];
        for (int gg = bp + 1; gg <= b; gg++) start[gg] = i;
        if (i == n - 1)
            for (int gg = b + 1; gg <= g; gg++) start[gg] = n;
    }
    __syncthreads();
    if (t < nb && hist[t] > 0) atomicAdd(&bktCnt[t], hist[t]);
}

// ---- in-block exclusive scan ------------------------------------------------
__device__ __forceinline__ int scan256_ex(int* sbuf, int v, int t) {
    sbuf[t] = v;
    __syncthreads();
    for (int off = 1; off < 256; off <<= 1) {
        int x = sbuf[t];
        int y = (t >= off) ? sbuf[t - off] : 0;
        __syncthreads();
        sbuf[t] = x + y;
        __syncthreads();
    }
    return sbuf[t] - v;
}

// ---- A2: partition edges; ebuf packed (ldst<<17)|src (N < 2^17) ------------
__global__ __launch_bounds__(256) void k_bkt_part(const int* __restrict__ row,
                                                  const int* __restrict__ col,
                                                  const int* __restrict__ bktCnt,
                                                  int* bktCur, unsigned int* __restrict__ ebuf,
                                                  int e, int nb) {
    __shared__ int sbuf[256];
    __shared__ int hist[256];
    __shared__ int base[256];
    __shared__ int lcur[256];
    int t = threadIdx.x;
    int boff = scan256_ex(sbuf, (t < nb) ? bktCnt[t] : 0, t);
    hist[t] = 0; lcur[t] = 0;
    __syncthreads();
    int bs = blockIdx.x * EPB;
    unsigned int pk[EPT];
    int b[EPT];
#pragma unroll
    for (int j = 0; j < EPT; j++) {
        int idx = bs + j * 256 + t;
        if (idx < e) {
            int c = col[idx];
            pk[j] = ((unsigned int)(c & (BSPAN - 1)) << 17) | (unsigned int)row[idx];
            b[j] = c >> 9;
            atomicAdd(&hist[b[j]], 1);
        } else b[j] = -1;
    }
    __syncthreads();
    if (t < nb && hist[t] > 0) base[t] = boff + atomicAdd(&bktCur[t], hist[t]);
    __syncthreads();
#pragma unroll
    for (int j = 0; j < EPT; j++) {
        if (b[j] >= 0) {
            int lofs = atomicAdd(&lcur[b[j]], 1);
            ebuf[base[b[j]] + lofs] = pk[j];
        }
    }
}

// ---- B: per-bucket hist+scan -> rowptr + dinv + CSR fill -------------------
__global__ __launch_bounds__(256) void k_bkt_build(const unsigned int* __restrict__ ebuf,
                                                   const int* __restrict__ bktCnt,
                                                   int* __restrict__ rowptr,
                                                   float* __restrict__ dinv,
                                                   int* __restrict__ eSrc,
                                                   int n, int nb) {
    __shared__ int sbuf[256];
    __shared__ int hist[BSPAN];
    __shared__ int cur[BSPAN];
    int t = threadIdx.x;
    int bkt = blockIdx.x;

    int boff_ex = scan256_ex(sbuf, (t < nb) ? bktCnt[t] : 0, t);
    __shared__ int boff_s, cnt_s;
    if (t == bkt) boff_s = boff_ex;
    if (t == 0) cnt_s = bktCnt[bkt];
    hist[t] = 0; hist[t + 256] = 0;
    __syncthreads();
    int es = boff_s, ee = boff_s + cnt_s;

    {
        int i = es + t;
        for (; i + 3 * 256 < ee; i += 4 * 256) {
            unsigned p0 = ebuf[i], p1 = ebuf[i + 256], p2 = ebuf[i + 512], p3 = ebuf[i + 768];
            atomicAdd(&hist[p0 >> 17], 1);
            atomicAdd(&hist[p1 >> 17], 1);
            atomicAdd(&hist[p2 >> 17], 1);
            atomicAdd(&hist[p3 >> 17], 1);
        }
        for (; i < ee; i += 256) atomicAdd(&hist[ebuf[i] >> 17], 1);
    }
    __syncthreads();

    int h0 = hist[2 * t], h1 = hist[2 * t + 1];
    __syncthreads();
    int ex = scan256_ex(sbuf, h0 + h1, t);
    int e0 = es + ex, e1 = e0 + h0;

    int node0 = bkt * BSPAN;
    int n0 = node0 + 2 * t, n1 = node0 + 2 * t + 1;
    if (n0 <= n) rowptr[n0] = e0;
    if (n1 <= n) rowptr[n1] = e1;
    if (n0 < n) dinv[n0] = rsqrtf((float)(h0 + 1));
    if (n1 < n) dinv[n1] = rsqrtf((float)(h1 + 1));
    cur[2 * t] = e0; cur[2 * t + 1] = e1;
    __syncthreads();

    {
        int i = es + t;
        for (; i + 3 * 256 < ee; i += 4 * 256) {
            unsigned p0 = ebuf[i], p1 = ebuf[i + 256], p2 = ebuf[i + 512], p3 = ebuf[i + 768];
            int s0 = atomicAdd(&cur[p0 >> 17], 1);
            int s1 = atomicAdd(&cur[p1 >> 17], 1);
            int s2 = atomicAdd(&cur[p2 >> 17], 1);
            int s3 = atomicAdd(&cur[p3 >> 17], 1);
            eSrc[s0] = (int)(p0 & 0x1FFFFu);
            eSrc[s1] = (int)(p1 & 0x1FFFFu);
            eSrc[s2] = (int)(p2 & 0x1FFFFu);
            eSrc[s3] = (int)(p3 & 0x1FFFFu);
        }
        for (; i < ee; i += 256) {
            unsigned int p = ebuf[i];
            int slot = atomicAdd(&cur[p >> 17], 1);
            eSrc[slot] = (int)(p & 0x1FFFFu);
        }
    }
}

// ---- xs = f16(dinv (x) x), padded row stride RS (standalone, full grid) ----
template <int F, int RS>
__global__ void k_prescale(const float* __restrict__ x, const float* __restrict__ dinv,
                           f16* __restrict__ xs, int n) {
    constexpr int CH = F / 2;
    int idx = blockIdx.x * blockDim.x + threadIdx.x;
    if (idx >= n * CH) return;
    int node = idx / CH;
    int c = idx - node * CH;
    float d = dinv[node];
    float2 v = *reinterpret_cast<const float2*>(x + (long long)node * F + c * 2);
    f16x2 h;
    h[0] = (f16)(v.x * d);
    h[1] = (f16)(v.y * d);
    *reinterpret_cast<f16x2*>(xs + (long long)node * RS + c * 2) = h;
}

// ---- wide gather, 8-deep predicated batch issue (standalone, layer 3) ------
template <int F, int RS>
__global__ __launch_bounds__(256) void k_gatherw(
        const int* __restrict__ rowptr, const int* __restrict__ eSrc,
        const float* __restrict__ dinv, const f16* __restrict__ hs,
        f16* __restrict__ out, int n) {
    constexpr int CGN = RS / 8;    // f16x8 chunks per row (16 for RS=128)
    constexpr int EPW = 64 / CGN;  // rows gathered per wave instr (4)
    int wave = threadIdx.x >> 6;
    int lane = threadIdx.x & 63;
    int eslot = lane / CGN;
    int cg = lane & (CGN - 1);
    int node = blockIdx.x * 4 + wave;
    if (node >= n) return;
    int ch0 = cg * 8;
    int lim = F - ch0;
    if (lim > 8) lim = 8;
    if (lim < 0) lim = 0;

    int rs_ = rowptr[node], re = rowptr[node + 1];
    float di = dinv[node];
    int deg = re - rs_;
    int myidx = 0;
    if (lane < deg) myidx = eSrc[rs_ + lane];

    const f16x8* src = reinterpret_cast<const f16x8*>(hs);
    float acc[8];
#pragma unroll
    for (int j = 0; j < 8; j++) acc[j] = 0.f;

    if (eslot == 0) {
        f16x8 v = src[(long long)node * CGN + cg];
#pragma unroll
        for (int j = 0; j < 8; j++) acc[j] += (float)v[j];
    }

    int nfull = deg < 64 ? deg : 64;
    for (int base = 0; base < nfull; base += 8 * EPW) {
        int sidx[8];
#pragma unroll
        for (int u = 0; u < 8; u++) {
            int idx = base + u * EPW + eslot;
            sidx[u] = __shfl(myidx, idx < 63 ? idx : 63);
        }
        f16x8 v[8];
#pragma unroll
        for (int u = 0; u < 8; u++) {
            int idx = base + u * EPW + eslot;
            if (idx < nfull) v[u] = src[(long long)sidx[u] * CGN + cg];
        }
#pragma unroll
        for (int u = 0; u < 8; u++) {
            int idx = base + u * EPW + eslot;
            if (idx < nfull) {
#pragma unroll
                for (int j = 0; j < 8; j++) acc[j] += (float)v[u][j];
            }
        }
    }
    for (int e = rs_ + 64 + eslot; e < re; e += EPW) {
        int s = eSrc[e];
        f16x8 v = src[(long long)s * CGN + cg];
#pragma unroll
        for (int j = 0; j < 8; j++) acc[j] += (float)v[j];
    }

#pragma unroll
    for (int j = 0; j < 8; j++)
        if (j >= lim) acc[j] = 0.f;
#pragma unroll
    for (int m = CGN; m < 64; m <<= 1)
#pragma unroll
        for (int j = 0; j < 8; j++) acc[j] += __shfl_xor(acc[j], m);

    if (eslot == 0) {
        f16x8 o;
#pragma unroll
        for (int j = 0; j < 8; j++) o[j] = (f16)(acc[j] * di);
        *reinterpret_cast<f16x8*>(out + (long long)node * RS + ch0) = o;
    }
}

// ---- fused gather + MFMA GEMM, 4 waves (layers 1/2: F=54, KPAD=64) ---------
// Wave owns a 16-node strip; TWO nodes concurrent per step (32-lane halves,
// 4 edge-slots x 8 chan-groups each); 8 pair-steps. Gather uses 8-deep
// predicated batch covering edges [0,32) in one issue burst. MFMA: each wave
// computes all NT tiles for its 16-row group.
template <int F, int KTILES, int NTILES, int FOUT, int OSTR>
__global__ __launch_bounds__(256) void k_gcn_fused(
        const int* __restrict__ rowptr, const int* __restrict__ eSrc,
        const float* __restrict__ dinv, const f16* __restrict__ hs,
        const f16* __restrict__ Wb, const float* __restrict__ bias,
        f16* __restrict__ outh, int n) {
    constexpr int KPAD = KTILES * 32;   // 64 == input row stride RS
    constexpr int KP   = KPAD + 8;
    constexpr int CGN  = KPAD / 8;      // 8 f16x8 chunks per row
    constexpr int EPH  = 32 / CGN;      // 4 edge slots per half

    __shared__ __align__(16) f16 a_lds[64 * KP];

    int t = threadIdx.x;
    int node0 = blockIdx.x * 64;
    int w = t >> 6;             // 0..3
    int lane = t & 63;
    int half = lane >> 5;
    int l = lane & 31;
    int eslot = l / CGN;        // 0..3
    int cg = l & (CGN - 1);
    int ch0 = cg * 8;
    int lim = F - ch0;
    if (lim > 8) lim = 8;
    if (lim < 0) lim = 0;
    int lbase = half * 32;

    const f16x8* src = reinterpret_cast<const f16x8*>(hs);
    int nodeBase = node0 + w * 16;

    // ---- gather phase: 8 pair-steps, each half owns one node ----
    for (int i = 0; i < 8; i++) {
        int node = nodeBase + 2 * i + half;
        float acc[8];
#pragma unroll
        for (int j = 0; j < 8; j++) acc[j] = 0.f;
        float di = 0.f;

        if (node < n) {
            int rs_ = rowptr[node], re = rowptr[node + 1];
            di = dinv[node];
            int deg = re - rs_;
            int myidx = 0;
            if (l < deg) myidx = eSrc[rs_ + l];   // contiguous across halves

            // self term (edge-slot 0 of each half)
            if (eslot == 0) {
                f16x8 v = src[(long long)node * CGN + cg];
#pragma unroll
                for (int j = 0; j < 8; j++) acc[j] += (float)v[j];
            }

            int nfull = deg < 32 ? deg : 32;
            if (nfull > 0) {
                int sidx[8];
#pragma unroll
                for (int u = 0; u < 8; u++) {
                    int idx = u * EPH + eslot;
                    sidx[u] = __shfl(myidx, lbase + (idx < 31 ? idx : 31));
                }
                f16x8 v[8];
#pragma unroll
                for (int u = 0; u < 8; u++) {
                    int idx = u * EPH + eslot;
                    if (idx < nfull) v[u] = src[(long long)sidx[u] * CGN + cg];
                }
#pragma unroll
                for (int u = 0; u < 8; u++) {
                    int idx = u * EPH + eslot;
                    if (idx < nfull) {
#pragma unroll
                        for (int j = 0; j < 8; j++) acc[j] += (float)v[u][j];
                    }
                }
            }
            // overflow beyond 32 preloaded edges (P(deg>32) small)
            for (int e = rs_ + 32 + eslot; e < re; e += EPH) {
                int s = eSrc[e];
                f16x8 v = src[(long long)s * CGN + cg];
#pragma unroll
                for (int j = 0; j < 8; j++) acc[j] += (float)v[j];
            }

            // kill pad-channel garbage before the cross-slot reduce
#pragma unroll
            for (int j = 0; j < 8; j++)
                if (j >= lim) acc[j] = 0.f;
            // sum over edge-slot bits within the half (m = 8, 16)
#pragma unroll
            for (int m = CGN; m < 32; m <<= 1)
#pragma unroll
                for (int j = 0; j < 8; j++) acc[j] += __shfl_xor(acc[j], m);
        }

        if (eslot == 0) {
            f16x8 o;
#pragma unroll
            for (int j = 0; j < 8; j++) o[j] = (f16)(acc[j] * di);
            *reinterpret_cast<f16x8*>(&a_lds[(w * 16 + 2 * i + half) * KP + ch0]) = o;
        }
    }
    __syncthreads();

    // ---- MFMA phase ----
    int quad = lane >> 4;
    int col = lane & 15;

    f16x8 afr[KTILES];
#pragma unroll
    for (int kt = 0; kt < KTILES; kt++)
        afr[kt] = *reinterpret_cast<const f16x8*>(
            &a_lds[(16 * w + col) * KP + kt * 32 + quad * 8]);

    int nodeC = node0 + 16 * w + quad * 4;
    float dv[4];
#pragma unroll
    for (int r = 0; r < 4; r++) {
        int nd = nodeC + r;
        dv[r] = (nd < n) ? dinv[nd] : 0.f;
    }

    const f16x8* wb = reinterpret_cast<const f16x8*>(Wb);
#pragma unroll
    for (int nt = 0; nt < NTILES; nt++) {
        f16x8 bfr[KTILES];
#pragma unroll
        for (int kt = 0; kt < KTILES; kt++)
            bfr[kt] = wb[(nt * KTILES + kt) * 64 + lane];
        f32x4 acc = {0.f, 0.f, 0.f, 0.f};
#pragma unroll
        for (int kt = 0; kt < KTILES; kt++)
            acc = __builtin_amdgcn_mfma_f32_16x16x32_f16(afr[kt], bfr[kt], acc, 0, 0, 0);

        int ch = nt * 16 + col;
        if (ch < FOUT) {
            float bval = bias[ch];
#pragma unroll
            for (int r = 0; r < 4; r++) {
                int nd = nodeC + r;
                if (nd < n)
                    outh[(long long)nd * OSTR + ch] =
                        (f16)(fmaxf(acc[r] + bval, 0.f) * dv[r]);
            }
        }
    }
}

// ---- MFMA node GEMM with fused mean-pool (layer 3) -------------------------
template <int KTILES, int NTILES, int K, int FOUT>
__global__ __launch_bounds__(256) void k_gemm_pool(
        const f16* __restrict__ in, const f16* __restrict__ Wb,
        const float* __restrict__ bias, const int* __restrict__ batch,
        float* __restrict__ psum, int n) {
    constexpr int KPAD = KTILES * 32;
    constexpr int KP   = KPAD + 8;
    constexpr int V8   = KPAD / 8;
    constexpr int NSLOT = 4;

    __shared__ f16 a_lds[64 * KP];
    __shared__ float psum_l[NSLOT * FOUT];

    int t = threadIdx.x;
    int node0 = blockIdx.x * 64;

    const f16x8* inp = reinterpret_cast<const f16x8*>(in);
    for (int f = t; f < 64 * V8; f += 256) {
        int node = f / V8;
        int v = f - node * V8;
        f16x8 val = {};
        if (node0 + node < n) val = inp[(long long)(node0 + node) * V8 + v];
        *reinterpret_cast<f16x8*>(&a_lds[node * KP + v * 8]) = val;
    }
    for (int i = t; i < NSLOT * FOUT; i += 256) psum_l[i] = 0.f;
    __syncthreads();

    int w = t >> 6;
    int lane = t & 63;
    int quad = lane >> 4;
    int col = lane & 15;

    f16x8 afr[KTILES];
#pragma unroll
    for (int kt = 0; kt < KTILES; kt++)
        afr[kt] = *reinterpret_cast<const f16x8*>(
            &a_lds[(16 * w + col) * KP + kt * 32 + quad * 8]);

    int nodeC = node0 + 16 * w + quad * 4;
    int gb[4];
#pragma unroll
    for (int r = 0; r < 4; r++) {
        int nd = nodeC + r;
        gb[r] = (nd < n) ? batch[nd] : -1;
    }
    int g0 = batch[node0];

    const f16x8* wb = reinterpret_cast<const f16x8*>(Wb);
#pragma unroll
    for (int nt = 0; nt < NTILES; nt++) {
        f16x8 bfr[KTILES];
#pragma unroll
        for (int kt = 0; kt < KTILES; kt++)
            bfr[kt] = wb[(nt * KTILES + kt) * 64 + lane];
        f32x4 acc = {0.f, 0.f, 0.f, 0.f};
#pragma unroll
        for (int kt = 0; kt < KTILES; kt++)
            acc = __builtin_amdgcn_mfma_f32_16x16x32_f16(afr[kt], bfr[kt], acc, 0, 0, 0);

        int ch = nt * 16 + col;
        if (ch < FOUT) {
            float bval = bias[ch];
            if (gb[0] == gb[3] && gb[0] >= 0) {
                float s = fmaxf(acc[0] + bval, 0.f) + fmaxf(acc[1] + bval, 0.f)
                        + fmaxf(acc[2] + bval, 0.f) + fmaxf(acc[3] + bval, 0.f);
                int slot = gb[0] - g0;
                if (slot < NSLOT) atomicAdd(&psum_l[slot * FOUT + ch], s);
                else atomicAdd(&psum[gb[0] * FOUT + ch], s);
            } else {
#pragma unroll
                for (int r = 0; r < 4; r++) {
                    if (gb[r] < 0) continue;
                    float v = fmaxf(acc[r] + bval, 0.f);
                    int slot = gb[r] - g0;
                    if (slot < NSLOT) atomicAdd(&psum_l[slot * FOUT + ch], v);
                    else atomicAdd(&psum[gb[r] * FOUT + ch], v);
                }
            }
        }
    }

    __syncthreads();
    int lastNode = node0 + 63;
    if (lastNode >= n) lastNode = n - 1;
    int nsl = batch[lastNode] - g0 + 1;
    if (nsl > NSLOT) nsl = NSLOT;
    for (int f = t; f < nsl * FOUT; f += 256) {
        float v = psum_l[f];
        if (v != 0.f) atomicAdd(&psum[(g0 + f / FOUT) * FOUT + (f % FOUT)], v);
    }
}

// ---- FC layers (split; fc1 folds the mean divide) --------------------------
__global__ void k_fc1(const float* __restrict__ P, const int* __restrict__ start,
                      const float* __restrict__ W, const float* __restrict__ bias,
                      float* __restrict__ out) {
    int row = blockIdx.x >> 2;
    int o = (blockIdx.x & 3) * 256 + threadIdx.x;
    int cnt = start[row + 1] - start[row];
    float scale = 1.0f / fmaxf((float)cnt, 1.0f);
    __shared__ float prow[216];
    if (threadIdx.x < 216) prow[threadIdx.x] = P[row * 216 + threadIdx.x] * scale;
    __syncthreads();
    float acc = bias[o];
    for (int k = 0; k < 216; k++) acc += prow[k] * W[k * 1024 + o];
    out[row * 1024 + o] = fmaxf(acc, 0.f);
}
__global__ void k_fc2(const float* __restrict__ G, const float* __restrict__ W,
                      const float* __restrict__ bias, float* __restrict__ out) {
    int row = blockIdx.x;
    int o = threadIdx.x;  // 128
    __shared__ float grow[1024];
    for (int k = threadIdx.x; k < 1024; k += 128) grow[k] = G[row * 1024 + k];
    __syncthreads();
    float acc = bias[o];
    for (int k = 0; k < 1024; k++) acc += grow[k] * W[k * 128 + o];
    out[row * 128 + o] = acc;
}

// ---------------------------------------------------------------------------
extern "C" void kernel_launch(void* const* d_in, const int* in_sizes, int n_in,
                              void* d_out, int out_size, void* d_ws, size_t ws_size,
                              hipStream_t stream) {
    const float* x     = (const float*)d_in[0];
    const int*   ei    = (const int*)d_in[1];
    const int*   batch = (const int*)d_in[2];
    const float* W1  = (const float*)d_in[3];
    const float* b1  = (const float*)d_in[4];
    const float* W2  = (const float*)d_in[5];
    const float* b2  = (const float*)d_in[6];
    const float* W3  = (const float*)d_in[7];
    const float* b3  = (const float*)d_in[8];
    const float* Wf1 = (const float*)d_in[9];
    const float* bf1 = (const float*)d_in[10];
    const float* Wf2 = (const float*)d_in[11];
    const float* bf2 = (const float*)d_in[12];
    float* out = (float*)d_out;

    const int N = in_sizes[0] / 54;   // 100000 (< 2^17 for ebuf packing)
    const int E = in_sizes[1] / 2;    // 1600000
    const int G = 256;
    const int* row = ei;
    const int* col = ei + E;
    const int NB = cdiv(N, BSPAN);    // 196
    const int NBLK_A = cdiv(E, EPB);

    // workspace carve-up (256B aligned)
    char* ws = (char*)d_ws;
    size_t off = 0;
    auto carve = [&](size_t bytes) {
        void* p = ws + off;
        off += (bytes + 255) & ~(size_t)255;
        return p;
    };
    int*   rowptr  = (int*)carve((size_t)(N + 1) * 4);
    int*   bktCnt  = (int*)carve(256 * 4);
    int*   bktCur  = (int*)carve(256 * 4);
    int*   eSrc    = (int*)carve((size_t)E * 4);
    float* dinv    = (float*)carve((size_t)N * 4);
    f16*   xs      = (f16*)carve((size_t)N * 64 * 2);    // F=54 padded to 64
    f16*   hsbuf   = (f16*)carve((size_t)N * 128 * 2);   // ping (stride 64 or 128)
    f16*   bufA    = (f16*)carve((size_t)N * 128 * 2);   // pong
    unsigned int* ebuf = (unsigned int*)carve((size_t)E * 4);
    float* psum    = (float*)carve((size_t)G * 216 * 4);
    float* gbuf    = (float*)carve((size_t)G * 1024 * 4);
    int*   start   = (int*)carve((size_t)(G + 1) * 4);
    f16*   w1b     = (f16*)carve((size_t)4 * 2 * 512 * 2);
    f16*   w2b     = (f16*)carve((size_t)7 * 2 * 512 * 2);
    f16*   w3b     = (f16*)carve((size_t)14 * 4 * 512 * 2);

    const int T = 256;
    // bktCnt must be zero before k_init's cross-block atomic accumulation
    hipMemsetAsync(bktCnt, 0, 256 * 4, stream);

    // ---- combined init (zero + weight pack + boundaries + bucket hist) ----
    int gInit = cdiv(N, T) > NBLK_A ? cdiv(N, T) : NBLK_A;
    k_init<<<gInit, T, 0, stream>>>(batch, start, psum, bktCnt, bktCur, col,
                                    W1, W2, W3, w1b, w2b, w3b, E, NB, N, G);

    // ---- bucketed CSR build: part -> build ----
    k_bkt_part<<<NBLK_A, 256, 0, stream>>>(row, col, bktCnt, bktCur, ebuf, E, NB);
    k_bkt_build<<<NB, 256, 0, stream>>>(ebuf, bktCnt, rowptr, dinv, eSrc, N, NB);

    // ---- prescale (standalone, full grid) ----
    k_prescale<54, 64><<<cdiv(N * 27, T), T, 0, stream>>>(x, dinv, xs, N);

    const int GB = cdiv(N, 64);

    // ---- layer 1 (fused): xs -> hsbuf (54ch, stride 64) ----
    k_gcn_fused<54, 2, 4, 54, 64><<<GB, 256, 0, stream>>>(
        rowptr, eSrc, dinv, xs, w1b, b1, hsbuf, N);

    // ---- layer 2 (fused): hsbuf -> bufA (108ch, stride 128) ----
    k_gcn_fused<54, 2, 7, 108, 128><<<GB, 256, 0, stream>>>(
        rowptr, eSrc, dinv, hsbuf, w2b, b2, bufA, N);

    // ---- layer 3 (split): gather108 bufA -> hsbuf, then GEMM+pool ----
    k_gatherw<108, 128><<<cdiv(N, 4), 256, 0, stream>>>(rowptr, eSrc, dinv, bufA, hsbuf, N);
    k_gemm_pool<4, 14, 108, 216><<<GB, 256, 0, stream>>>(
        hsbuf, w3b, b3, batch, psum, N);

    // ---- FC head (split) ----
    k_fc1<<<G * 4, T, 0, stream>>>(psum, start, Wf1, bf1, gbuf);
    k_fc2<<<G, 128, 0, stream>>>(gbuf, Wf2, bf2, out);
}

// Round 11
// 360.729 us; speedup vs baseline: 1.1065x; 1.0524x over previous
//
#include <hip/hip_runtime.h>

// ---------------------------------------------------------------------------
// ProteinGCNNet: 3x GCNConv + mean-pool + 2 FC layers.
// Round 26: pipeline the fused gather WITHOUT violating vmcnt drain order
// (R20's lesson: prefetch issued BEFORE rows forces vmcnt->0; here prefetch
// is issued AFTER the row batch, so accumulate waits only vmcnt(2)).
// Per wave-strip: 17 rowptr + 16 dinv coalesced-preloaded once (shfl
// distributed) -> per-step rowptr/dinv loads gone; per pair-step: issue row
// batch -> issue next pair's eSrc idx + self-row -> accumulate. Exposed
// serial latency per step: ~3 VMEM round-trips -> ~1.
// Everything else = R25 (379.6us best): 256-thr/4-wave fused kernels, 8-deep
// predicated batches, k_init+hist fusion, split L3, bucketed CSR, fused pool.
// ---------------------------------------------------------------------------

typedef _Float16 f16;
typedef _Float16 f16x2 __attribute__((ext_vector_type(2)));
typedef _Float16 f16x8 __attribute__((ext_vector_type(8)));
typedef float f32x4 __attribute__((ext_vector_type(4)));

static __host__ __device__ inline int cdiv(int a, int b) { return (a + b - 1) / b; }

constexpr int BSPAN = 512;
constexpr int EPB   = 4096;
constexpr int EPT   = EPB / 256;

// ---- MFMA weight pack helper ----------------------------------------------
__device__ __forceinline__ void wpack_one(const float* W, f16* Wb, int K, int F,
                                          int KT, int idx) {
    int j = idx & 7;
    int lane = (idx >> 3) & 63;
    int fi = idx >> 9;
    int kt = fi % KT;
    int nt = fi / KT;
    int k = kt * 32 + (lane >> 4) * 8 + j;
    int nn = nt * 16 + (lane & 15);
    Wb[idx] = (k < K && nn < F) ? (f16)W[k * F + nn] : (f16)0.f;
}

// ---- combined init: zero + weight pack + boundaries + bucket histogram -----
__global__ __launch_bounds__(256) void k_init(
        const int* __restrict__ batch, int* __restrict__ start,
        float* __restrict__ psum, int* __restrict__ bktCnt, int* __restrict__ bktCur,
        const int* __restrict__ col,
        const float* __restrict__ W1, const float* __restrict__ W2,
        const float* __restrict__ W3, f16* __restrict__ w1b,
        f16* __restrict__ w2b, f16* __restrict__ w3b,
        int e, int nb, int n, int g) {
    __shared__ int hist[256];
    int t = threadIdx.x;
    int i = blockIdx.x * blockDim.x + t;
    hist[t] = 0;
    __syncthreads();
    int ebase = blockIdx.x * EPB;
#pragma unroll
    for (int j = 0; j < EPT; j++) {
        int idx = ebase + j * 256 + t;
        if (idx < e) atomicAdd(&hist[col[idx] >> 9], 1);
    }
    if (i < g * 216) psum[i] = 0.f;
    if (i < 256) bktCur[i] = 0;
    constexpr int T1 = 4 * 2 * 512;
    constexpr int T2 = 7 * 2 * 512;
    constexpr int T3 = 14 * 4 * 512;
    if (i < T1) wpack_one(W1, w1b, 54, 54, 2, i);
    else if (i < T1 + T2) wpack_one(W2, w2b, 54, 108, 2, i - T1);
    else if (i < T1 + T2 + T3) wpack_one(W3, w3b, 108, 216, 4, i - T1 - T2);
    if (i < n) {
        int b = batch[i];
        int bp = (i == 0) ? -1 : batch[i - 1];
        for (int gg = bp + 1; gg <= b; gg++) start[gg] = i;
        if (i == n - 1)
            for (int gg = b + 1; gg <= g; gg++) start[gg] = n;
    }
    __syncthreads();
    if (t < nb && hist[t] > 0) atomicAdd(&bktCnt[t], hist[t]);
}

// ---- in-block exclusive scan ------------------------------------------------
__device__ __forceinline__ int scan256_ex(int* sbuf, int v, int t) {
    sbuf[t] = v;
    __syncthreads();
    for (int off = 1; off < 256; off <<= 1) {
        int x = sbuf[t];
        int y = (t >= off) ? sbuf[t - off] : 0;
        __syncthreads();
        sbuf[t] = x + y;
        __syncthreads();
    }
    return sbuf[t] - v;
}

// ---- A2: partition edges; ebuf packed (ldst<<17)|src (N < 2^17) ------------
__global__ __launch_bounds__(256) void k_bkt_part(const int* __restrict__ row,
                                                  const int* __restrict__ col,
                                                  const int* __restrict__ bktCnt,
                                                  int* bktCur, unsigned int* __restrict__ ebuf,
                                                  int e, int nb) {
    __shared__ int sbuf[256];
    __shared__ int hist[256];
    __shared__ int base[256];
    __shared__ int lcur[256];
    int t = threadIdx.x;
    int boff = scan256_ex(sbuf, (t < nb) ? bktCnt[t] : 0, t);
    hist[t] = 0; lcur[t] = 0;
    __syncthreads();
    int bs = blockIdx.x * EPB;
    unsigned int pk[EPT];
    int b[EPT];
#pragma unroll
    for (int j = 0; j < EPT; j++) {
        int idx = bs + j * 256 + t;
        if (idx < e) {
            int c = col[idx];
            pk[j] = ((unsigned int)(c & (BSPAN - 1)) << 17) | (unsigned int)row[idx];
            b[j] = c >> 9;
            atomicAdd(&hist[b[j]], 1);
        } else b[j] = -1;
    }
    __syncthreads();
    if (t < nb && hist[t] > 0) base[t] = boff + atomicAdd(&bktCur[t], hist[t]);
    __syncthreads();
#pragma unroll
    for (int j = 0; j < EPT; j++) {
        if (b[j] >= 0) {
            int lofs = atomicAdd(&lcur[b[j]], 1);
            ebuf[base[b[j]] + lofs] = pk[j];
        }
    }
}

// ---- B: per-bucket hist+scan -> rowptr + dinv + CSR fill -------------------
__global__ __launch_bounds__(256) void k_bkt_build(const unsigned int* __restrict__ ebuf,
                                                   const int* __restrict__ bktCnt,
                                                   int* __restrict__ rowptr,
                                                   float* __restrict__ dinv,
                                                   int* __restrict__ eSrc,
                                                   int n, int nb) {
    __shared__ int sbuf[256];
    __shared__ int hist[BSPAN];
    __shared__ int cur[BSPAN];
    int t = threadIdx.x;
    int bkt = blockIdx.x;

    int boff_ex = scan256_ex(sbuf, (t < nb) ? bktCnt[t] : 0, t);
    __shared__ int boff_s, cnt_s;
    if (t == bkt) boff_s = boff_ex;
    if (t == 0) cnt_s = bktCnt[bkt];
    hist[t] = 0; hist[t + 256] = 0;
    __syncthreads();
    int es = boff_s, ee = boff_s + cnt_s;

    {
        int i = es + t;
        for (; i + 3 * 256 < ee; i += 4 * 256) {
            unsigned p0 = ebuf[i], p1 = ebuf[i + 256], p2 = ebuf[i + 512], p3 = ebuf[i + 768];
            atomicAdd(&hist[p0 >> 17], 1);
            atomicAdd(&hist[p1 >> 17], 1);
            atomicAdd(&hist[p2 >> 17], 1);
            atomicAdd(&hist[p3 >> 17], 1);
        }
        for (; i < ee; i += 256) atomicAdd(&hist[ebuf[i] >> 17], 1);
    }
    __syncthreads();

    int h0 = hist[2 * t], h1 = hist[2 * t + 1];
    __syncthreads();
    int ex = scan256_ex(sbuf, h0 + h1, t);
    int e0 = es + ex, e1 = e0 + h0;

    int node0 = bkt * BSPAN;
    int n0 = node0 + 2 * t, n1 = node0 + 2 * t + 1;
    if (n0 <= n) rowptr[n0] = e0;
    if (n1 <= n) rowptr[n1] = e1;
    if (n0 < n) dinv[n0] = rsqrtf((float)(h0 + 1));
    if (n1 < n) dinv[n1] = rsqrtf((float)(h1 + 1));
    cur[2 * t] = e0; cur[2 * t + 1] = e1;
    __syncthreads();

    {
        int i = es + t;
        for (; i + 3 * 256 < ee; i += 4 * 256) {
            unsigned p0 = ebuf[i], p1 = ebuf[i + 256], p2 = ebuf[i + 512], p3 = ebuf[i + 768];
            int s0 = atomicAdd(&cur[p0 >> 17], 1);
            int s1 = atomicAdd(&cur[p1 >> 17], 1);
            int s2 = atomicAdd(&cur[p2 >> 17], 1);
            int s3 = atomicAdd(&cur[p3 >> 17], 1);
            eSrc[s0] = (int)(p0 & 0x1FFFFu);
            eSrc[s1] = (int)(p1 & 0x1FFFFu);
            eSrc[s2] = (int)(p2 & 0x1FFFFu);
            eSrc[s3] = (int)(p3 & 0x1FFFFu);
        }
        for (; i < ee; i += 256) {
            unsigned int p = ebuf[i];
            int slot = atomicAdd(&cur[p >> 17], 1);
            eSrc[slot] = (int)(p & 0x1FFFFu);
        }
    }
}

// ---- xs = f16(dinv (x) x), padded row stride RS (standalone, full grid) ----
template <int F, int RS>
__global__ void k_prescale(const float* __restrict__ x, const float* __restrict__ dinv,
                           f16* __restrict__ xs, int n) {
    constexpr int CH = F / 2;
    int idx = blockIdx.x * blockDim.x + threadIdx.x;
    if (idx >= n * CH) return;
    int node = idx / CH;
    int c = idx - node * CH;
    float d = dinv[node];
    float2 v = *reinterpret_cast<const float2*>(x + (long long)node * F + c * 2);
    f16x2 h;
    h[0] = (f16)(v.x * d);
    h[1] = (f16)(v.y * d);
    *reinterpret_cast<f16x2*>(xs + (long long)node * RS + c * 2) = h;
}

// ---- wide gather, 8-deep predicated batch issue (standalone, layer 3) ------
template <int F, int RS>
__global__ __launch_bounds__(256) void k_gatherw(
        const int* __restrict__ rowptr, const int* __restrict__ eSrc,
        const float* __restrict__ dinv, const f16* __restrict__ hs,
        f16* __restrict__ out, int n) {
    constexpr int CGN = RS / 8;    // f16x8 chunks per row (16 for RS=128)
    constexpr int EPW = 64 / CGN;  // rows gathered per wave instr (4)
    int wave = threadIdx.x >> 6;
    int lane = threadIdx.x & 63;
    int eslot = lane / CGN;
    int cg = lane & (CGN - 1);
    int node = blockIdx.x * 4 + wave;
    if (node >= n) return;
    int ch0 = cg * 8;
    int lim = F - ch0;
    if (lim > 8) lim = 8;
    if (lim < 0) lim = 0;

    int rs_ = rowptr[node], re = rowptr[node + 1];
    float di = dinv[node];
    int deg = re - rs_;
    int myidx = 0;
    if (lane < deg) myidx = eSrc[rs_ + lane];

    const f16x8* src = reinterpret_cast<const f16x8*>(hs);
    float acc[8];
#pragma unroll
    for (int j = 0; j < 8; j++) acc[j] = 0.f;

    if (eslot == 0) {
        f16x8 v = src[(long long)node * CGN + cg];
#pragma unroll
        for (int j = 0; j < 8; j++) acc[j] += (float)v[j];
    }

    int nfull = deg < 64 ? deg : 64;
    for (int base = 0; base < nfull; base += 8 * EPW) {
        int sidx[8];
#pragma unroll
        for (int u = 0; u < 8; u++) {
            int idx = base + u * EPW + eslot;
            sidx[u] = __shfl(myidx, idx < 63 ? idx : 63);
        }
        f16x8 v[8];
#pragma unroll
        for (int u = 0; u < 8; u++) {
            int idx = base + u * EPW + eslot;
            if (idx < nfull) v[u] = src[(long long)sidx[u] * CGN + cg];
        }
#pragma unroll
        for (int u = 0; u < 8; u++) {
            int idx = base + u * EPW + eslot;
            if (idx < nfull) {
#pragma unroll
                for (int j = 0; j < 8; j++) acc[j] += (float)v[u][j];
            }
        }
    }
    for (int e = rs_ + 64 + eslot; e < re; e += EPW) {
        int s = eSrc[e];
        f16x8 v = src[(long long)s * CGN + cg];
#pragma unroll
        for (int j = 0; j < 8; j++) acc[j] += (float)v[j];
    }

#pragma unroll
    for (int j = 0; j < 8; j++)
        if (j >= lim) acc[j] = 0.f;
#pragma unroll
    for (int m = CGN; m < 64; m <<= 1)
#pragma unroll
        for (int j = 0; j < 8; j++) acc[j] += __shfl_xor(acc[j], m);

    if (eslot == 0) {
        f16x8 o;
#pragma unroll
        for (int j = 0; j < 8; j++) o[j] = (f16)(acc[j] * di);
        *reinterpret_cast<f16x8*>(out + (long long)node * RS + ch0) = o;
    }
}

// ---- fused gather + MFMA GEMM, 4 waves (layers 1/2: F=54, KPAD=64) ---------
// Wave owns a 16-node strip; TWO nodes concurrent per step (32-lane halves).
// Pipelined: 17 rowptr + 16 dinv preloaded coalesced (shfl-distributed);
// per step: issue current pair's 8-row batch, THEN issue next pair's eSrc
// idx + self-row (younger loads -> accumulate waits only vmcnt(2)), then
// accumulate/reduce/LDS-write. One exposed VMEM latency per step.
template <int F, int KTILES, int NTILES, int FOUT, int OSTR>
__global__ __launch_bounds__(256) void k_gcn_fused(
        const int* __restrict__ rowptr, const int* __restrict__ eSrc,
        const float* __restrict__ dinv, const f16* __restrict__ hs,
        const f16* __restrict__ Wb, const float* __restrict__ bias,
        f16* __restrict__ outh, int n) {
    constexpr int KPAD = KTILES * 32;   // 64 == input row stride RS
    constexpr int KP   = KPAD + 8;
    constexpr int CGN  = KPAD / 8;      // 8 f16x8 chunks per row
    constexpr int EPH  = 32 / CGN;      // 4 edge slots per half

    __shared__ __align__(16) f16 a_lds[64 * KP];

    int t = threadIdx.x;
    int node0 = blockIdx.x * 64;
    int w = t >> 6;             // 0..3
    int lane = t & 63;
    int half = lane >> 5;
    int l = lane & 31;
    int eslot = l / CGN;        // 0..3
    int cg = l & (CGN - 1);
    int ch0 = cg * 8;
    int lim = F - ch0;
    if (lim > 8) lim = 8;
    if (lim < 0) lim = 0;
    int lbase = half * 32;

    const f16x8* src = reinterpret_cast<const f16x8*>(hs);
    int nodeBase = node0 + w * 16;

    // ---- wave-strip preloads (one coalesced VMEM each) ----
    int rpIdx = nodeBase + (lane < 17 ? lane : 16);
    if (rpIdx > n) rpIdx = n;
    int rp = rowptr[rpIdx];
    int dvIdx = nodeBase + (lane < 16 ? lane : 15);
    if (dvIdx > n - 1) dvIdx = n - 1;
    float dvl = dinv[dvIdx];

    // ---- prologue: pair 0 setup ----
    int rs_c = __shfl(rp, half);
    int re_c = __shfl(rp, 1 + half);
    int deg_c = re_c - rs_c;
    int my_c = 0;
    if (l < deg_c) my_c = eSrc[rs_c + l];
    f16x8 sv_c = {};
    if (eslot == 0 && nodeBase + half < n)
        sv_c = src[(long long)(nodeBase + half) * CGN + cg];

    // ---- gather phase: 8 pair-steps, each half owns one node ----
    for (int i = 0; i < 8; i++) {
        int node = nodeBase + 2 * i + half;
        int nfull = deg_c < 32 ? deg_c : 32;

        // 1. issue current pair's row batch (oldest loads in queue)
        int sidx[8];
#pragma unroll
        for (int u = 0; u < 8; u++) {
            int idx = u * EPH + eslot;
            sidx[u] = __shfl(my_c, lbase + (idx < 31 ? idx : 31));
        }
        f16x8 v[8];
#pragma unroll
        for (int u = 0; u < 8; u++) {
            int idx = u * EPH + eslot;
            if (idx < nfull) v[u] = src[(long long)sidx[u] * CGN + cg];
        }

        // 2. prefetch next pair (younger loads; stay in flight across step)
        int rs_n = 0, re_n = 0, deg_n = 0, my_n = 0;
        f16x8 sv_n = {};
        if (i < 7) {
            rs_n = __shfl(rp, 2 * i + 2 + half);
            re_n = __shfl(rp, 2 * i + 3 + half);
            deg_n = re_n - rs_n;
            if (l < deg_n) my_n = eSrc[rs_n + l];
            int node2 = nodeBase + 2 * i + 2 + half;
            if (eslot == 0 && node2 < n)
                sv_n = src[(long long)node2 * CGN + cg];
        }

        // 3. accumulate (compiler waits for rows only: vmcnt(prefetch))
        float acc[8];
#pragma unroll
        for (int j = 0; j < 8; j++) acc[j] = 0.f;
        if (eslot == 0) {
#pragma unroll
            for (int j = 0; j < 8; j++) acc[j] += (float)sv_c[j];
        }
#pragma unroll
        for (int u = 0; u < 8; u++) {
            int idx = u * EPH + eslot;
            if (idx < nfull) {
#pragma unroll
                for (int j = 0; j < 8; j++) acc[j] += (float)v[u][j];
            }
        }
        // overflow beyond 32 preloaded edges (P(deg>32) small)
        for (int e = rs_c + 32 + eslot; e < re_c; e += EPH) {
            int s = eSrc[e];
            f16x8 vv = src[(long long)s * CGN + cg];
#pragma unroll
            for (int j = 0; j < 8; j++) acc[j] += (float)vv[j];
        }

        // kill pad-channel garbage before the cross-slot reduce
#pragma unroll
        for (int j = 0; j < 8; j++)
            if (j >= lim) acc[j] = 0.f;
        // sum over edge-slot bits within the half (m = 8, 16)
#pragma unroll
        for (int m = CGN; m < 32; m <<= 1)
#pragma unroll
            for (int j = 0; j < 8; j++) acc[j] += __shfl_xor(acc[j], m);

        float di = (node < n) ? __shfl(dvl, 2 * i + half) : 0.f;
        if (eslot == 0) {
            f16x8 o;
#pragma unroll
            for (int j = 0; j < 8; j++) o[j] = (f16)(acc[j] * di);
            *reinterpret_cast<f16x8*>(&a_lds[(w * 16 + 2 * i + half) * KP + ch0]) = o;
        }
        rs_c = rs_n; re_c = re_n; deg_c = deg_n; my_c = my_n; sv_c = sv_n;
    }
    __syncthreads();

    // ---- MFMA phase ----
    int quad = lane >> 4;
    int col = lane & 15;

    f16x8 afr[KTILES];
#pragma unroll
    for (int kt = 0; kt < KTILES; kt++)
        afr[kt] = *reinterpret_cast<const f16x8*>(
            &a_lds[(16 * w + col) * KP + kt * 32 + quad * 8]);

    int nodeC = node0 + 16 * w + quad * 4;
    float dv[4];
#pragma unroll
    for (int r = 0; r < 4; r++) {
        int nd = nodeC + r;
        dv[r] = (nd < n) ? dinv[nd] : 0.f;
    }

    const f16x8* wb = reinterpret_cast<const f16x8*>(Wb);
#pragma unroll
    for (int nt = 0; nt < NTILES; nt++) {
        f16x8 bfr[KTILES];
#pragma unroll
        for (int kt = 0; kt < KTILES; kt++)
            bfr[kt] = wb[(nt * KTILES + kt) * 64 + lane];
        f32x4 acc = {0.f, 0.f, 0.f, 0.f};
#pragma unroll
        for (int kt = 0; kt < KTILES; kt++)
            acc = __builtin_amdgcn_mfma_f32_16x16x32_f16(afr[kt], bfr[kt], acc, 0, 0, 0);

        int ch = nt * 16 + col;
        if (ch < FOUT) {
            float bval = bias[ch];
#pragma unroll
            for (int r = 0; r < 4; r++) {
                int nd = nodeC + r;
                if (nd < n)
                    outh[(long long)nd * OSTR + ch] =
                        (f16)(fmaxf(acc[r] + bval, 0.f) * dv[r]);
            }
        }
    }
}

// ---- MFMA node GEMM with fused mean-pool (layer 3) -------------------------
template <int KTILES, int NTILES, int K, int FOUT>
__global__ __launch_bounds__(256) void k_gemm_pool(
        const f16* __restrict__ in, const f16* __restrict__ Wb,
        const float* __restrict__ bias, const int* __restrict__ batch,
        float* __restrict__ psum, int n) {
    constexpr int KPAD = KTILES * 32;
    constexpr int KP   = KPAD + 8;
    constexpr int V8   = KPAD / 8;
    constexpr int NSLOT = 4;

    __shared__ f16 a_lds[64 * KP];
    __shared__ float psum_l[NSLOT * FOUT];

    int t = threadIdx.x;
    int node0 = blockIdx.x * 64;

    const f16x8* inp = reinterpret_cast<const f16x8*>(in);
    for (int f = t; f < 64 * V8; f += 256) {
        int node = f / V8;
        int v = f - node * V8;
        f16x8 val = {};
        if (node0 + node < n) val = inp[(long long)(node0 + node) * V8 + v];
        *reinterpret_cast<f16x8*>(&a_lds[node * KP + v * 8]) = val;
    }
    for (int i = t; i < NSLOT * FOUT; i += 256) psum_l[i] = 0.f;
    __syncthreads();

    int w = t >> 6;
    int lane = t & 63;
    int quad = lane >> 4;
    int col = lane & 15;

    f16x8 afr[KTILES];
#pragma unroll
    for (int kt = 0; kt < KTILES; kt++)
        afr[kt] = *reinterpret_cast<const f16x8*>(
            &a_lds[(16 * w + col) * KP + kt * 32 + quad * 8]);

    int nodeC = node0 + 16 * w + quad * 4;
    int gb[4];
#pragma unroll
    for (int r = 0; r < 4; r++) {
        int nd = nodeC + r;
        gb[r] = (nd < n) ? batch[nd] : -1;
    }
    int g0 = batch[node0];

    const f16x8* wb = reinterpret_cast<const f16x8*>(Wb);
#pragma unroll
    for (int nt = 0; nt < NTILES; nt++) {
        f16x8 bfr[KTILES];
#pragma unroll
        for (int kt = 0; kt < KTILES; kt++)
            bfr[kt] = wb[(nt * KTILES + kt) * 64 + lane];
        f32x4 acc = {0.f, 0.f, 0.f, 0.f};
#pragma unroll
        for (int kt = 0; kt < KTILES; kt++)
            acc = __builtin_amdgcn_mfma_f32_16x16x32_f16(afr[kt], bfr[kt], acc, 0, 0, 0);

        int ch = nt * 16 + col;
        if (ch < FOUT) {
            float bval = bias[ch];
            if (gb[0] == gb[3] && gb[0] >= 0) {
                float s = fmaxf(acc[0] + bval, 0.f) + fmaxf(acc[1] + bval, 0.f)
                        + fmaxf(acc[2] + bval, 0.f) + fmaxf(acc[3] + bval, 0.f);
                int slot = gb[0] - g0;
                if (slot < NSLOT) atomicAdd(&psum_l[slot * FOUT + ch], s);
                else atomicAdd(&psum[gb[0] * FOUT + ch], s);
            } else {
#pragma unroll
                for (int r = 0; r < 4; r++) {
                    if (gb[r] < 0) continue;
                    float v = fmaxf(acc[r] + bval, 0.f);
                    int slot = gb[r] - g0;
                    if (slot < NSLOT) atomicAdd(&psum_l[slot * FOUT + ch], v);
                    else atomicAdd(&psum[gb[r] * FOUT + ch], v);
                }
            }
        }
    }

    __syncthreads();
    int lastNode = node0 + 63;
    if (lastNode >= n) lastNode = n - 1;
    int nsl = batch[lastNode] - g0 + 1;
    if (nsl > NSLOT) nsl = NSLOT;
    for (int f = t; f < nsl * FOUT; f += 256) {
        float v = psum_l[f];
        if (v != 0.f) atomicAdd(&psum[(g0 + f / FOUT) * FOUT + (f % FOUT)], v);
    }
}

// ---- FC layers (split; fc1 folds the mean divide) --------------------------
__global__ void k_fc1(const float* __restrict__ P, const int* __restrict__ start,
                      const float* __restrict__ W, const float* __restrict__ bias,
                      float* __restrict__ out) {
    int row = blockIdx.x >> 2;
    int o = (blockIdx.x & 3) * 256 + threadIdx.x;
    int cnt = start[row + 1] - start[row];
    float scale = 1.0f / fmaxf((float)cnt, 1.0f);
    __shared__ float prow[216];
    if (threadIdx.x < 216) prow[threadIdx.x] = P[row * 216 + threadIdx.x] * scale;
    __syncthreads();
    float acc = bias[o];
    for (int k = 0; k < 216; k++) acc += prow[k] * W[k * 1024 + o];
    out[row * 1024 + o] = fmaxf(acc, 0.f);
}
__global__ void k_fc2(const float* __restrict__ G, const float* __restrict__ W,
                      const float* __restrict__ bias, float* __restrict__ out) {
    int row = blockIdx.x;
    int o = threadIdx.x;  // 128
    __shared__ float grow[1024];
    for (int k = threadIdx.x; k < 1024; k += 128) grow[k] = G[row * 1024 + k];
    __syncthreads();
    float acc = bias[o];
    for (int k = 0; k < 1024; k++) acc += grow[k] * W[k * 128 + o];
    out[row * 128 + o] = acc;
}

// ---------------------------------------------------------------------------
extern "C" void kernel_launch(void* const* d_in, const int* in_sizes, int n_in,
                              void* d_out, int out_size, void* d_ws, size_t ws_size,
                              hipStream_t stream) {
    const float* x     = (const float*)d_in[0];
    const int*   ei    = (const int*)d_in[1];
    const int*   batch = (const int*)d_in[2];
    const float* W1  = (const float*)d_in[3];
    const float* b1  = (const float*)d_in[4];
    const float* W2  = (const float*)d_in[5];
    const float* b2  = (const float*)d_in[6];
    const float* W3  = (const float*)d_in[7];
    const float* b3  = (const float*)d_in[8];
    const float* Wf1 = (const float*)d_in[9];
    const float* bf1 = (const float*)d_in[10];
    const float* Wf2 = (const float*)d_in[11];
    const float* bf2 = (const float*)d_in[12];
    float* out = (float*)d_out;

    const int N = in_sizes[0] / 54;   // 100000 (< 2^17 for ebuf packing)
    const int E = in_sizes[1] / 2;    // 1600000
    const int G = 256;
    const int* row = ei;
    const int* col = ei + E;
    const int NB = cdiv(N, BSPAN);    // 196
    const int NBLK_A = cdiv(E, EPB);

    // workspace carve-up (256B aligned)
    char* ws = (char*)d_ws;
    size_t off = 0;
    auto carve = [&](size_t bytes) {
        void* p = ws + off;
        off += (bytes + 255) & ~(size_t)255;
        return p;
    };
    int*   rowptr  = (int*)carve((size_t)(N + 1) * 4);
    int*   bktCnt  = (int*)carve(256 * 4);
    int*   bktCur  = (int*)carve(256 * 4);
    int*   eSrc    = (int*)carve((size_t)E * 4);
    float* dinv    = (float*)carve((size_t)N * 4);
    f16*   xs      = (f16*)carve((size_t)N * 64 * 2);    // F=54 padded to 64
    f16*   hsbuf   = (f16*)carve((size_t)N * 128 * 2);   // ping (stride 64 or 128)
    f16*   bufA    = (f16*)carve((size_t)N * 128 * 2);   // pong
    unsigned int* ebuf = (unsigned int*)carve((size_t)E * 4);
    float* psum    = (float*)carve((size_t)G * 216 * 4);
    float* gbuf    = (float*)carve((size_t)G * 1024 * 4);
    int*   start   = (int*)carve((size_t)(G + 1) * 4);
    f16*   w1b     = (f16*)carve((size_t)4 * 2 * 512 * 2);
    f16*   w2b     = (f16*)carve((size_t)7 * 2 * 512 * 2);
    f16*   w3b     = (f16*)carve((size_t)14 * 4 * 512 * 2);

    const int T = 256;
    // bktCnt must be zero before k_init's cross-block atomic accumulation
    hipMemsetAsync(bktCnt, 0, 256 * 4, stream);

    // ---- combined init (zero + weight pack + boundaries + bucket hist) ----
    int gInit = cdiv(N, T) > NBLK_A ? cdiv(N, T) : NBLK_A;
    k_init<<<gInit, T, 0, stream>>>(batch, start, psum, bktCnt, bktCur, col,
                                    W1, W2, W3, w1b, w2b, w3b, E, NB, N, G);

    // ---- bucketed CSR build: part -> build ----
    k_bkt_part<<<NBLK_A, 256, 0, stream>>>(row, col, bktCnt, bktCur, ebuf, E, NB);
    k_bkt_build<<<NB, 256, 0, stream>>>(ebuf, bktCnt, rowptr, dinv, eSrc, N, NB);

    // ---- prescale (standalone, full grid) ----
    k_prescale<54, 64><<<cdiv(N * 27, T), T, 0, stream>>>(x, dinv, xs, N);

    const int GB = cdiv(N, 64);

    // ---- layer 1 (fused): xs -> hsbuf (54ch, stride 64) ----
    k_gcn_fused<54, 2, 4, 54, 64><<<GB, 256, 0, stream>>>(
        rowptr, eSrc, dinv, xs, w1b, b1, hsbuf, N);

    // ---- layer 2 (fused): hsbuf -> bufA (108ch, stride 128) ----
    k_gcn_fused<54, 2, 7, 108, 128><<<GB, 256, 0, stream>>>(
        rowptr, eSrc, dinv, hsbuf, w2b, b2, bufA, N);

    // ---- layer 3 (split): gather108 bufA -> hsbuf, then GEMM+pool ----
    k_gatherw<108, 128><<<cdiv(N, 4), 256, 0, stream>>>(rowptr, eSrc, dinv, bufA, hsbuf, N);
    k_gemm_pool<4, 14, 108, 216><<<GB, 256, 0, stream>>>(
        hsbuf, w3b, b3, batch, psum, N);

    // ---- FC head (split) ----
    k_fc1<<<G * 4, T, 0, stream>>>(psum, start, Wf1, bf1, gbuf);
    k_fc2<<<G, 128, 0, stream>>>(gbuf, Wf2, bf2, out);
}